// Round 9
// baseline (596.822 us; speedup 1.0000x reference)
//
#include <hip/hip_runtime.h>
#include <hip/hip_bf16.h>

#define N_NODES 100000
#define N_EDGES 1600000
#define N_GRAPHS 128
#define IN_F 128
#define H_F 128
#define OUT_F 64
#define HID 10
#define NCLS 10
#define XPAD 136    // LDS row stride in bf16 (pad 128 -> 136: 16-way conflict -> free 2-way)
#define BSH 7                     // bucket = node >> 7 (128-node windows)
#define NBUCK 782                 // ceil(100000/128)
#define SBLK 128                  // edge partitions for hist/scatter
#define EPB (N_EDGES / SBLK)      // 12500, exact
#define NB_PREP 4

typedef __attribute__((ext_vector_type(8))) short bf16x8;
typedef __attribute__((ext_vector_type(4))) float f32x4;

__device__ __forceinline__ float bl(unsigned int u) { return __uint_as_float(u << 16); }
__device__ __forceinline__ float bh(unsigned int u) { return __uint_as_float(u & 0xffff0000u); }

// ---------------- phase 1: LDS-privatized bucket histograms (dst & src) + weight prep ----------------
__global__ __launch_bounds__(1024) void k_hist2(const int* __restrict__ src, const int* __restrict__ dst,
                                                int* __restrict__ Pd, int* __restrict__ Ps,
                                                const float* __restrict__ W1, const float* __restrict__ W2,
                                                unsigned short* __restrict__ Wt1, unsigned short* __restrict__ Wt2) {
    __shared__ int hd[NBUCK];
    __shared__ int hs[NBUCK];
    const int blk = blockIdx.x;
    if (blk < SBLK) {
        for (int i = threadIdx.x; i < NBUCK; i += 1024) { hd[i] = 0; hs[i] = 0; }
        __syncthreads();
        const int base = blk * EPB;
        for (int i = threadIdx.x; i < EPB; i += 1024) {
            atomicAdd(&hd[dst[base + i] >> BSH], 1);
            atomicAdd(&hs[src[base + i] >> BSH], 1);
        }
        __syncthreads();
        for (int b = threadIdx.x; b < NBUCK; b += 1024) {
            Pd[b * SBLK + blk] = hd[b];
            Ps[b * SBLK + blk] = hs[b];
        }
    } else {
        int t = (blk - SBLK) * 1024 + threadIdx.x;
        const int stride = NB_PREP * 1024;
        for (int i = t; i < 128 * 128; i += stride) {
            int c = i >> 7, k = i & 127;
            __hip_bfloat16 v = __float2bfloat16(W1[k * 128 + c]);
            Wt1[i] = *(unsigned short*)&v;
        }
        for (int i = t; i < 64 * 128; i += stride) {
            int c = i >> 7, k = i & 127;
            __hip_bfloat16 v = __float2bfloat16(W2[k * 64 + c]);
            Wt2[i] = *(unsigned short*)&v;
        }
    }
}

// ---------------- phase 2a: per-bucket scan across blocks (exclusive), emit totals ----------------
__global__ __launch_bounds__(128) void k_scanA(int* __restrict__ Pd, int* __restrict__ Ps,
                                               int* __restrict__ Td, int* __restrict__ Ts) {
    __shared__ int sc[128];
    const int b = blockIdx.x;
    const int t = threadIdx.x;
    int* P = (b < NBUCK) ? Pd : Ps;
    int* T = (b < NBUCK) ? Td : Ts;
    const int bb = (b < NBUCK) ? b : b - NBUCK;
    int v = P[bb * SBLK + t];
    sc[t] = v;
    __syncthreads();
    for (int off = 1; off < 128; off <<= 1) {
        int u = (t >= off) ? sc[t - off] : 0;
        __syncthreads();
        sc[t] += u;
        __syncthreads();
    }
    P[bb * SBLK + t] = sc[t] - v;    // exclusive within bucket
    if (t == 127) T[bb] = sc[127];
}

// ---------------- phase 2b: scan bucket totals -> global bases (with total at [NBUCK]) ----------------
__global__ __launch_bounds__(1024) void k_scanB(const int* __restrict__ Td, const int* __restrict__ Ts,
                                                int* __restrict__ Bd, int* __restrict__ Bs) {
    __shared__ int sc[1024];
    const int t = threadIdx.x;
    int v = (t < NBUCK) ? Td[t] : 0;
    sc[t] = v;
    __syncthreads();
    for (int off = 1; off < 1024; off <<= 1) {
        int u = (t >= off) ? sc[t - off] : 0;
        __syncthreads();
        sc[t] += u;
        __syncthreads();
    }
    if (t < NBUCK) Bd[t] = sc[t] - v;
    if (t == NBUCK - 1) Bd[NBUCK] = sc[t];
    __syncthreads();
    int v2 = (t < NBUCK) ? Ts[t] : 0;
    sc[t] = v2;
    __syncthreads();
    for (int off = 1; off < 1024; off <<= 1) {
        int u = (t >= off) ? sc[t - off] : 0;
        __syncthreads();
        sc[t] += u;
        __syncthreads();
    }
    if (t < NBUCK) Bs[t] = sc[t] - v2;
    if (t == NBUCK - 1) Bs[NBUCK] = sc[t];
}

// ---------------- phase 3: bucketed scatter, role-split, packed payloads ----------------
// blocks [0,SBLK): dst-bucketed pairs packed as (src<<7)|(dst&127)  (src < 2^17)
// blocks [SBLK,2*SBLK): src-bucketed bytes (src&127)
__global__ __launch_bounds__(1024) void k_scatter(const int* __restrict__ src, const int* __restrict__ dst,
                                                  const int* __restrict__ Pd, const int* __restrict__ Ps,
                                                  const int* __restrict__ Bd, const int* __restrict__ Bs,
                                                  unsigned int* __restrict__ pb, unsigned char* __restrict__ sb) {
    __shared__ int tk[NBUCK];
    const int b = blockIdx.x;
    const bool isPb = b < SBLK;
    const int blk = isPb ? b : b - SBLK;
    for (int i = threadIdx.x; i < NBUCK; i += 1024) tk[i] = 0;
    __syncthreads();
    const int base = blk * EPB;
    if (isPb) {
        for (int i = threadIdx.x; i < EPB; i += 1024) {
            int d = dst[base + i];
            int s = src[base + i];
            int bd = d >> BSH;
            int t = atomicAdd(&tk[bd], 1);
            pb[Bd[bd] + Pd[bd * SBLK + blk] + t] = ((unsigned)s << 7) | (unsigned)(d & 127);
        }
    } else {
        for (int i = threadIdx.x; i < EPB; i += 1024) {
            int s = src[base + i];
            int bs = s >> BSH;
            int t = atomicAdd(&tk[bs], 1);
            sb[Bs[bs] + Ps[bs * SBLK + blk] + t] = (unsigned char)(s & 127);
        }
    }
}

// ---------------- phase 4: tight CSR (cols+rp) + cnt_in + cnt_out per 128-node bucket ----------------
__global__ __launch_bounds__(256) void k_finalize(const unsigned int* __restrict__ pb, const int* __restrict__ Bd,
                                                  const unsigned char* __restrict__ sb, const int* __restrict__ Bs,
                                                  int* __restrict__ rp, int* __restrict__ cnt_in,
                                                  int* __restrict__ cnt_out, int* __restrict__ cols) {
    __shared__ int cnt[128];
    __shared__ int exc[128];
    __shared__ int tick[128];
    __shared__ int h[128];
    __shared__ int sc[128];
    const int b = blockIdx.x;
    const int tid = threadIdx.x;
    if (tid < 128) { cnt[tid] = 0; tick[tid] = 0; h[tid] = 0; }
    __syncthreads();
    const int e0 = Bd[b], e1 = Bd[b + 1];
    for (int i = e0 + tid; i < e1; i += 256) atomicAdd(&cnt[pb[i] & 127], 1);
    const int f0 = Bs[b], f1 = Bs[b + 1];
    for (int i = f0 + tid; i < f1; i += 256) atomicAdd(&h[sb[i]], 1);
    __syncthreads();
    if (tid < 128) sc[tid] = cnt[tid];
    __syncthreads();
    for (int off = 1; off < 128; off <<= 1) {
        int u = (tid < 128 && tid >= off) ? sc[tid - off] : 0;
        __syncthreads();
        if (tid < 128) sc[tid] += u;
        __syncthreads();
    }
    if (tid < 128) exc[tid] = sc[tid] - cnt[tid];
    __syncthreads();
    const int node0 = b << BSH;
    if (tid < 128 && node0 + tid < N_NODES) {
        rp[node0 + tid] = e0 + exc[tid];
        cnt_in[node0 + tid] = cnt[tid];
        cnt_out[node0 + tid] = h[tid];
    }
    for (int i = e0 + tid; i < e1; i += 256) {
        unsigned int p = pb[i];
        int loc = p & 127;
        int t = atomicAdd(&tick[loc], 1);
        cols[e0 + exc[loc] + t] = (int)(p >> 7);
    }
}

// ---------------- MFMA GEMM: sliced output G[slice][v][16] = ro[v]*(X[v,:]@W[:,slice cols])
// X: f32 row-major (XBF16=false) or sliced bf16 [slice][node][16] (XBF16=true). K=128.
template <int TOTF, bool XBF16>
__global__ __launch_bounds__(256) void k_gemm_mfma(const void* __restrict__ Xv,
                                                   const unsigned short* __restrict__ Wt,
                                                   const int* __restrict__ cnt_out,
                                                   unsigned short* __restrict__ Gout) {
    __shared__ __align__(16) unsigned short Xs[32 * XPAD];
    __shared__ __align__(16) unsigned short Ws[64 * XPAD];
    const int tid = threadIdx.x;
    const int cbase = blockIdx.y * 64;
    const int row0 = blockIdx.x * 32;  // N_NODES % 32 == 0

    if constexpr (XBF16) {
        // X is sliced bf16: [slice][node][16], read as uints (2 cols each)
        const unsigned int* Xu = (const unsigned int*)Xv;
#pragma unroll
        for (int j = 0; j < 8; j++) {
            int i = tid + 256 * j;           // 2048 uints = 32 rows x 64 col-pairs
            int r = i >> 6, cu = i & 63;     // cu: uint col-pair 0..63 (cols 2cu,2cu+1)
            int slice = cu >> 3, off = cu & 7;
            unsigned int u = Xu[(size_t)slice * N_NODES * 8 + (size_t)(row0 + r) * 8 + off];
            *(unsigned int*)&Xs[r * XPAD + cu * 2] = u;
        }
    } else {
        const float4* X4 = (const float4*)Xv;  // row = 32 float4
#pragma unroll
        for (int j = 0; j < 4; j++) {
            int i = tid + 256 * j;
            int r = i >> 5, k4 = i & 31;
            float4 x = X4[(size_t)(row0 + r) * 32 + k4];
            __hip_bfloat162 lo = __float22bfloat162_rn({x.x, x.y});
            __hip_bfloat162 hi = __float22bfloat162_rn({x.z, x.w});
            uint2 u;
            u.x = *(unsigned int*)&lo;
            u.y = *(unsigned int*)&hi;
            *(uint2*)&Xs[r * XPAD + k4 * 4] = u;
        }
    }
    {
        const uint2* W2 = (const uint2*)Wt;  // row = 32 uint2
#pragma unroll
        for (int j = 0; j < 8; j++) {
            int i = tid + 256 * j;
            int c = i >> 5, kk = i & 31;
            uint2 u = W2[(size_t)(cbase + c) * 32 + kk];
            *(uint2*)&Ws[c * XPAD + kk * 4] = u;
        }
    }
    __syncthreads();

    const int lane = tid & 63;
    const int wv = tid >> 6;
    const int m = lane & 15;
    const int q = lane >> 4;
    const int roff = (wv & 1) * 16;
    const int coff = (wv >> 1) * 32;

    f32x4 acc0 = {0.f, 0.f, 0.f, 0.f}, acc1 = {0.f, 0.f, 0.f, 0.f};
#pragma unroll
    for (int ks = 0; ks < 4; ks++) {
        int kb = ks * 32 + q * 8;
        bf16x8 a  = *(const bf16x8*)&Xs[(roff + m) * XPAD + kb];
        bf16x8 b0 = *(const bf16x8*)&Ws[(coff + m) * XPAD + kb];
        bf16x8 b1 = *(const bf16x8*)&Ws[(coff + 16 + m) * XPAD + kb];
        acc0 = __builtin_amdgcn_mfma_f32_16x16x32_bf16(a, b0, acc0, 0, 0, 0);
        acc1 = __builtin_amdgcn_mfma_f32_16x16x32_bf16(a, b1, acc1, 0, 0, 0);
    }
    const int sbase = (cbase + coff) >> 4;   // slice of first 16-col subtile; second is sbase+1
#pragma unroll
    for (int r = 0; r < 4; r++) {
        int row = row0 + roff + q * 4 + r;
        float s = rsqrtf((float)max(cnt_out[row], 1));
        __hip_bfloat16 o0 = __float2bfloat16(acc0[r] * s);
        __hip_bfloat16 o1 = __float2bfloat16(acc1[r] * s);
        Gout[(size_t)sbase * N_NODES * 16 + (size_t)row * 16 + m]       = *(unsigned short*)&o0;
        Gout[(size_t)(sbase + 1) * N_NODES * 16 + (size_t)row * 16 + m] = *(unsigned short*)&o1;
    }
}

// ---------------- sliced SpMM: H[slice][v][16] = relu(rsqrt(deg)*sum_{s} G[slice][s][16] + bias)
// slice = blockIdx.x % NSLICE -> XCD affinity keeps one 3.2 MB slice resident per XCD L2.
// wave = 8 groups x 8 lanes; group processes one neighbor's 32 B slice row (uint = 2 cols/lane).
template <int NSLICE>
__global__ __launch_bounds__(256) void k_spmm_s(const unsigned int* __restrict__ Gu,
                                                const int* __restrict__ rp,
                                                const int* __restrict__ cnt_in,
                                                const int* __restrict__ cols,
                                                const float* __restrict__ bias,
                                                unsigned int* __restrict__ Hu) {
    const int slice = blockIdx.x % NSLICE;
    const int chunk = blockIdx.x / NSLICE;
    const int lane = threadIdx.x & 63;
    const int wave = threadIdx.x >> 6;
    const int v = chunk * 4 + wave;       // N_NODES % 4 == 0, grid exact
    const int gl = lane & 7;              // col-pair within slice
    const int g = lane >> 3;              // neighbor sub-slot
    const unsigned int* Gs = Gu + (size_t)slice * N_NODES * 8;
    const int deg = cnt_in[v];
    const int b0 = rp[v];
    float ax = 0.f, ay = 0.f;
    for (int base = 0; base < deg; base += 64) {
        int n = min(64, deg - base);
        int mycol = (lane < n) ? cols[b0 + base + lane] : 0;
        for (int j = g; j < n; j += 8) {
            int s = __shfl(mycol, j);
            unsigned int u = Gs[(size_t)s * 8 + gl];
            ax += bl(u);
            ay += bh(u);
        }
    }
    ax += __shfl_xor(ax, 8); ax += __shfl_xor(ax, 16); ax += __shfl_xor(ax, 32);
    ay += __shfl_xor(ay, 8); ay += __shfl_xor(ay, 16); ay += __shfl_xor(ay, 32);
    if (g == 0) {
        float r = rsqrtf((float)max(deg, 1));
        float2 b = *(const float2*)&bias[slice * 16 + 2 * gl];
        __hip_bfloat162 p = __float22bfloat162_rn({fmaxf(fmaf(ax, r, b.x), 0.f),
                                                   fmaxf(fmaf(ay, r, b.y), 0.f)});
        Hu[(size_t)slice * N_NODES * 8 + (size_t)v * 8 + gl] = *(unsigned int*)&p;
    }
}

// ---------------- fused pooling + MLP + softmax (block per graph; h2 sliced bf16) ----------------
__global__ __launch_bounds__(256) void k_poolmlp(const unsigned short* __restrict__ h2s,
                                                 const int* __restrict__ gid,
                                                 const float* __restrict__ fcW1,
                                                 const float* __restrict__ fcb1,
                                                 const float* __restrict__ fcW2,
                                                 const float* __restrict__ fcb2,
                                                 float* __restrict__ out) {
    __shared__ int se[2];
    __shared__ float part[4][64];
    __shared__ float p[64];
    __shared__ float z[10];
    __shared__ float l[10];
    __shared__ float red[2];
    const int g = blockIdx.x;
    const int tid = threadIdx.x;  // 256
    if (tid < 2) {
        int target = g + tid;  // lower_bound over sorted gid
        int lo = 0, hi = N_NODES;
        while (lo < hi) {
            int mid = (lo + hi) >> 1;
            if (gid[mid] < target) lo = mid + 1; else hi = mid;
        }
        se[tid] = lo;
    }
    __syncthreads();
    const int s = se[0], e = se[1];
    const int c = tid & 63;
    const int w = tid >> 6;
    const unsigned short* base = h2s + (size_t)(c >> 4) * N_NODES * 16 + (c & 15);
    float acc = 0.f;
    for (int v = s + w; v < e; v += 4)
        acc += __uint_as_float(((unsigned int)base[(size_t)v * 16]) << 16);
    part[w][c] = acc;
    __syncthreads();
    if (tid < 64) {
        float t = part[0][tid] + part[1][tid] + part[2][tid] + part[3][tid];
        p[tid] = t / (float)max(e - s, 1);
    }
    __syncthreads();
    if (tid < 10) {
        float a = fcb1[tid];
        for (int k = 0; k < 64; k++) a = fmaf(p[k], fcW1[k * 10 + tid], a);
        z[tid] = fmaxf(a, 0.f);
    }
    __syncthreads();
    if (tid < 10) {
        float a = fcb2[tid];
        for (int k = 0; k < 10; k++) a = fmaf(z[k], fcW2[k * 10 + tid], a);
        l[tid] = a;
    }
    __syncthreads();
    if (tid == 0) {
        float m = l[0];
        for (int i = 1; i < 10; i++) m = fmaxf(m, l[i]);
        float ssum = 0.f;
        for (int i = 0; i < 10; i++) ssum += expf(l[i] - m);
        red[0] = m;
        red[1] = ssum;
    }
    __syncthreads();
    if (tid < 10) out[g * 10 + tid] = expf(l[tid] - red[0]) / red[1];
}

// ---------------- host ----------------
extern "C" void kernel_launch(void* const* d_in, const int* in_sizes, int n_in,
                              void* d_out, int out_size, void* d_ws, size_t ws_size,
                              hipStream_t stream) {
    const float* feats = (const float*)d_in[0];
    const int* src = (const int*)d_in[1];
    const int* dst = (const int*)d_in[2];
    const int* gid = (const int*)d_in[3];
    const float* W1 = (const float*)d_in[4];
    const float* b1 = (const float*)d_in[5];
    const float* W2 = (const float*)d_in[6];
    const float* b2 = (const float*)d_in[7];
    const float* fcW1 = (const float*)d_in[8];
    const float* fcb1 = (const float*)d_in[9];
    const float* fcW2 = (const float*)d_in[10];
    const float* fcb2 = (const float*)d_in[11];
    float* out = (float*)d_out;

    char* w = (char*)d_ws;
    size_t off = 0;
    auto alloc = [&](size_t bytes) -> void* {
        void* p = w + off;
        off = (off + bytes + 255) & ~(size_t)255;
        return p;
    };
    int* cnt_out = (int*)alloc(N_NODES * 4);
    int* cnt_in  = (int*)alloc(N_NODES * 4);
    int* rp      = (int*)alloc(N_NODES * 4);
    int* cols    = (int*)alloc((size_t)N_EDGES * 4);                         // 6.4 MB tight CSR
    int* Pd      = (int*)alloc(NBUCK * SBLK * 4);                            // 400 KB
    int* Ps      = (int*)alloc(NBUCK * SBLK * 4);
    int* Td      = (int*)alloc(NBUCK * 4);
    int* Ts      = (int*)alloc(NBUCK * 4);
    int* Bd      = (int*)alloc((NBUCK + 1) * 4);
    int* Bs      = (int*)alloc((NBUCK + 1) * 4);
    unsigned int* pb  = (unsigned int*)alloc((size_t)N_EDGES * 4);           // 6.4 MB packed
    unsigned char* sb = (unsigned char*)alloc((size_t)N_EDGES);              // 1.6 MB
    unsigned short* Wt1 = (unsigned short*)alloc(128 * 128 * 2);
    unsigned short* Wt2 = (unsigned short*)alloc(64 * 128 * 2);
    unsigned short* g1 = (unsigned short*)alloc((size_t)N_NODES * 128 * 2);  // sliced bf16 [8][N][16]
    unsigned short* h1 = (unsigned short*)alloc((size_t)N_NODES * 128 * 2);  // sliced bf16 [8][N][16]
    unsigned short* g2 = (unsigned short*)alloc((size_t)N_NODES * 64 * 2);   // sliced bf16 [4][N][16]
    unsigned short* h2 = (unsigned short*)alloc((size_t)N_NODES * 64 * 2);   // sliced bf16 [4][N][16]

    // build pipeline (bucket sort; no scattered device atomics, no memsets)
    k_hist2<<<SBLK + NB_PREP, 1024, 0, stream>>>(src, dst, Pd, Ps, W1, W2, Wt1, Wt2);
    k_scanA<<<2 * NBUCK, 128, 0, stream>>>(Pd, Ps, Td, Ts);
    k_scanB<<<1, 1024, 0, stream>>>(Td, Ts, Bd, Bs);
    k_scatter<<<2 * SBLK, 1024, 0, stream>>>(src, dst, Pd, Ps, Bd, Bs, pb, sb);
    k_finalize<<<NBUCK, 256, 0, stream>>>(pb, Bd, sb, Bs, rp, cnt_in, cnt_out, cols);

    // layer 1
    k_gemm_mfma<128, false><<<dim3(N_NODES / 32, 2), 256, 0, stream>>>(feats, Wt1, cnt_out, g1);
    k_spmm_s<8><<<(N_NODES / 4) * 8, 256, 0, stream>>>((const unsigned int*)g1, rp, cnt_in, cols, b1,
                                                       (unsigned int*)h1);

    // layer 2
    k_gemm_mfma<64, true><<<dim3(N_NODES / 32, 1), 256, 0, stream>>>(h1, Wt2, cnt_out, g2);
    k_spmm_s<4><<<(N_NODES / 4) * 4, 256, 0, stream>>>((const unsigned int*)g2, rp, cnt_in, cols, b2,
                                                       (unsigned int*)h2);

    k_poolmlp<<<N_GRAPHS, 256, 0, stream>>>(h2, gid, fcW1, fcb1, fcW2, fcb2, out);
}

// Round 10
// 351.647 us; speedup vs baseline: 1.6972x; 1.6972x over previous
//
#include <hip/hip_runtime.h>
#include <hip/hip_bf16.h>

#define N_NODES 100000
#define N_EDGES 1600000
#define N_GRAPHS 128
#define IN_F 128
#define H_F 128
#define OUT_F 64
#define HID 10
#define NCLS 10
#define XPAD 136    // LDS row stride in bf16 (pad 128 -> 136: 16-way conflict -> free 2-way)
#define BSH 7                     // bucket = node >> 7 (128-node windows)
#define NBUCK 782                 // ceil(100000/128)
#define SBLK 128                  // edge partitions for hist/scatter
#define EPB (N_EDGES / SBLK)      // 12500, exact
#define NB_PREP 4

typedef __attribute__((ext_vector_type(8))) short bf16x8;
typedef __attribute__((ext_vector_type(4))) float f32x4;

__device__ __forceinline__ float bl(unsigned int u) { return __uint_as_float(u << 16); }
__device__ __forceinline__ float bh(unsigned int u) { return __uint_as_float(u & 0xffff0000u); }

// ---------------- phase 1: LDS-privatized bucket histograms (dst & src) + weight prep ----------------
__global__ __launch_bounds__(1024) void k_hist2(const int* __restrict__ src, const int* __restrict__ dst,
                                                int* __restrict__ Pd, int* __restrict__ Ps,
                                                const float* __restrict__ W1, const float* __restrict__ W2,
                                                unsigned short* __restrict__ Wt1, unsigned short* __restrict__ Wt2) {
    __shared__ int hd[NBUCK];
    __shared__ int hs[NBUCK];
    const int blk = blockIdx.x;
    if (blk < SBLK) {
        for (int i = threadIdx.x; i < NBUCK; i += 1024) { hd[i] = 0; hs[i] = 0; }
        __syncthreads();
        const int base = blk * EPB;
        for (int i = threadIdx.x; i < EPB; i += 1024) {
            atomicAdd(&hd[dst[base + i] >> BSH], 1);
            atomicAdd(&hs[src[base + i] >> BSH], 1);
        }
        __syncthreads();
        for (int b = threadIdx.x; b < NBUCK; b += 1024) {
            Pd[b * SBLK + blk] = hd[b];
            Ps[b * SBLK + blk] = hs[b];
        }
    } else {
        int t = (blk - SBLK) * 1024 + threadIdx.x;
        const int stride = NB_PREP * 1024;
        for (int i = t; i < 128 * 128; i += stride) {
            int c = i >> 7, k = i & 127;
            __hip_bfloat16 v = __float2bfloat16(W1[k * 128 + c]);
            Wt1[i] = *(unsigned short*)&v;
        }
        for (int i = t; i < 64 * 128; i += stride) {
            int c = i >> 7, k = i & 127;
            __hip_bfloat16 v = __float2bfloat16(W2[k * 64 + c]);
            Wt2[i] = *(unsigned short*)&v;
        }
    }
}

// ---------------- phase 2a: per-bucket scan across blocks (exclusive), emit totals ----------------
__global__ __launch_bounds__(128) void k_scanA(int* __restrict__ Pd, int* __restrict__ Ps,
                                               int* __restrict__ Td, int* __restrict__ Ts) {
    __shared__ int sc[128];
    const int b = blockIdx.x;
    const int t = threadIdx.x;
    int* P = (b < NBUCK) ? Pd : Ps;
    int* T = (b < NBUCK) ? Td : Ts;
    const int bb = (b < NBUCK) ? b : b - NBUCK;
    int v = P[bb * SBLK + t];
    sc[t] = v;
    __syncthreads();
    for (int off = 1; off < 128; off <<= 1) {
        int u = (t >= off) ? sc[t - off] : 0;
        __syncthreads();
        sc[t] += u;
        __syncthreads();
    }
    P[bb * SBLK + t] = sc[t] - v;    // exclusive within bucket
    if (t == 127) T[bb] = sc[127];
}

// ---------------- phase 2b: scan bucket totals -> global bases (with total at [NBUCK]) ----------------
__global__ __launch_bounds__(1024) void k_scanB(const int* __restrict__ Td, const int* __restrict__ Ts,
                                                int* __restrict__ Bd, int* __restrict__ Bs) {
    __shared__ int sc[1024];
    const int t = threadIdx.x;
    int v = (t < NBUCK) ? Td[t] : 0;
    sc[t] = v;
    __syncthreads();
    for (int off = 1; off < 1024; off <<= 1) {
        int u = (t >= off) ? sc[t - off] : 0;
        __syncthreads();
        sc[t] += u;
        __syncthreads();
    }
    if (t < NBUCK) Bd[t] = sc[t] - v;
    if (t == NBUCK - 1) Bd[NBUCK] = sc[t];
    __syncthreads();
    int v2 = (t < NBUCK) ? Ts[t] : 0;
    sc[t] = v2;
    __syncthreads();
    for (int off = 1; off < 1024; off <<= 1) {
        int u = (t >= off) ? sc[t - off] : 0;
        __syncthreads();
        sc[t] += u;
        __syncthreads();
    }
    if (t < NBUCK) Bs[t] = sc[t] - v2;
    if (t == NBUCK - 1) Bs[NBUCK] = sc[t];
}

// ---------------- phase 3: bucketed scatter, role-split, packed payloads ----------------
// blocks [0,SBLK): dst-bucketed pairs packed as (src<<7)|(dst&127)  (src < 2^17)
// blocks [SBLK,2*SBLK): src-bucketed bytes (src&127)
__global__ __launch_bounds__(1024) void k_scatter(const int* __restrict__ src, const int* __restrict__ dst,
                                                  const int* __restrict__ Pd, const int* __restrict__ Ps,
                                                  const int* __restrict__ Bd, const int* __restrict__ Bs,
                                                  unsigned int* __restrict__ pb, unsigned char* __restrict__ sb) {
    __shared__ int tk[NBUCK];
    const int b = blockIdx.x;
    const bool isPb = b < SBLK;
    const int blk = isPb ? b : b - SBLK;
    for (int i = threadIdx.x; i < NBUCK; i += 1024) tk[i] = 0;
    __syncthreads();
    const int base = blk * EPB;
    if (isPb) {
        for (int i = threadIdx.x; i < EPB; i += 1024) {
            int d = dst[base + i];
            int s = src[base + i];
            int bd = d >> BSH;
            int t = atomicAdd(&tk[bd], 1);
            pb[Bd[bd] + Pd[bd * SBLK + blk] + t] = ((unsigned)s << 7) | (unsigned)(d & 127);
        }
    } else {
        for (int i = threadIdx.x; i < EPB; i += 1024) {
            int s = src[base + i];
            int bs = s >> BSH;
            int t = atomicAdd(&tk[bs], 1);
            sb[Bs[bs] + Ps[bs * SBLK + blk] + t] = (unsigned char)(s & 127);
        }
    }
}

// ---------------- phase 4: tight CSR (cols+rp) + cnt_out per 128-node bucket ----------------
__global__ __launch_bounds__(256) void k_finalize(const unsigned int* __restrict__ pb, const int* __restrict__ Bd,
                                                  const unsigned char* __restrict__ sb, const int* __restrict__ Bs,
                                                  int* __restrict__ rp, int* __restrict__ cnt_out,
                                                  int* __restrict__ cols) {
    __shared__ int cnt[128];
    __shared__ int exc[128];
    __shared__ int tick[128];
    __shared__ int h[128];
    __shared__ int sc[128];
    const int b = blockIdx.x;
    const int tid = threadIdx.x;
    if (tid < 128) { cnt[tid] = 0; tick[tid] = 0; h[tid] = 0; }
    __syncthreads();
    const int e0 = Bd[b], e1 = Bd[b + 1];
    for (int i = e0 + tid; i < e1; i += 256) atomicAdd(&cnt[pb[i] & 127], 1);
    const int f0 = Bs[b], f1 = Bs[b + 1];
    for (int i = f0 + tid; i < f1; i += 256) atomicAdd(&h[sb[i]], 1);
    __syncthreads();
    if (tid < 128) sc[tid] = cnt[tid];
    __syncthreads();
    for (int off = 1; off < 128; off <<= 1) {
        int u = (tid < 128 && tid >= off) ? sc[tid - off] : 0;
        __syncthreads();
        if (tid < 128) sc[tid] += u;
        __syncthreads();
    }
    if (tid < 128) exc[tid] = sc[tid] - cnt[tid];
    __syncthreads();
    const int node0 = b << BSH;
    if (tid < 128 && node0 + tid < N_NODES) {
        rp[node0 + tid] = e0 + exc[tid];
        cnt_out[node0 + tid] = h[tid];
    }
    if (b == NBUCK - 1 && tid == 0) rp[N_NODES] = N_EDGES;
    for (int i = e0 + tid; i < e1; i += 256) {
        unsigned int p = pb[i];
        int loc = p & 127;
        int t = atomicAdd(&tick[loc], 1);
        cols[e0 + exc[loc] + t] = (int)(p >> 7);
    }
}

// ---------------- MFMA GEMM: G[v, cbase..+63] = rsqrt(deg_out[v]) * (X[v,:] @ W[:, cbase..+63])
// Row-major bf16 output, stride TOTF. X: f32 (XBF16=false) or bf16 (XBF16=true), row stride 128.
template <int TOTF, bool XBF16>
__global__ __launch_bounds__(256) void k_gemm_mfma(const void* __restrict__ Xv,
                                                   const unsigned short* __restrict__ Wt,
                                                   const int* __restrict__ cnt_out,
                                                   unsigned short* __restrict__ Gout) {
    __shared__ __align__(16) unsigned short Xs[32 * XPAD];
    __shared__ __align__(16) unsigned short Ws[64 * XPAD];
    const int tid = threadIdx.x;
    const int cbase = blockIdx.y * 64;
    const int row0 = blockIdx.x * 32;  // N_NODES % 32 == 0

    if constexpr (XBF16) {
        const uint2* X2 = (const uint2*)Xv;  // row = 32 uint2 (128 bf16)
#pragma unroll
        for (int j = 0; j < 4; j++) {
            int i = tid + 256 * j;
            int r = i >> 5, kk = i & 31;
            uint2 u = X2[(size_t)(row0 + r) * 32 + kk];
            *(uint2*)&Xs[r * XPAD + kk * 4] = u;
        }
    } else {
        const float4* X4 = (const float4*)Xv;  // row = 32 float4
#pragma unroll
        for (int j = 0; j < 4; j++) {
            int i = tid + 256 * j;
            int r = i >> 5, k4 = i & 31;
            float4 x = X4[(size_t)(row0 + r) * 32 + k4];
            __hip_bfloat162 lo = __float22bfloat162_rn({x.x, x.y});
            __hip_bfloat162 hi = __float22bfloat162_rn({x.z, x.w});
            uint2 u;
            u.x = *(unsigned int*)&lo;
            u.y = *(unsigned int*)&hi;
            *(uint2*)&Xs[r * XPAD + k4 * 4] = u;
        }
    }
    {
        const uint2* W2 = (const uint2*)Wt;  // row = 32 uint2
#pragma unroll
        for (int j = 0; j < 8; j++) {
            int i = tid + 256 * j;
            int c = i >> 5, kk = i & 31;
            uint2 u = W2[(size_t)(cbase + c) * 32 + kk];
            *(uint2*)&Ws[c * XPAD + kk * 4] = u;
        }
    }
    __syncthreads();

    const int lane = tid & 63;
    const int wv = tid >> 6;
    const int m = lane & 15;
    const int q = lane >> 4;
    const int roff = (wv & 1) * 16;
    const int coff = (wv >> 1) * 32;

    f32x4 acc0 = {0.f, 0.f, 0.f, 0.f}, acc1 = {0.f, 0.f, 0.f, 0.f};
#pragma unroll
    for (int ks = 0; ks < 4; ks++) {
        int kb = ks * 32 + q * 8;
        bf16x8 a  = *(const bf16x8*)&Xs[(roff + m) * XPAD + kb];
        bf16x8 b0 = *(const bf16x8*)&Ws[(coff + m) * XPAD + kb];
        bf16x8 b1 = *(const bf16x8*)&Ws[(coff + 16 + m) * XPAD + kb];
        acc0 = __builtin_amdgcn_mfma_f32_16x16x32_bf16(a, b0, acc0, 0, 0, 0);
        acc1 = __builtin_amdgcn_mfma_f32_16x16x32_bf16(a, b1, acc1, 0, 0, 0);
    }
#pragma unroll
    for (int r = 0; r < 4; r++) {
        int row = row0 + roff + q * 4 + r;
        float s = rsqrtf((float)max(cnt_out[row], 1));
        int col0 = cbase + coff + m;
        __hip_bfloat16 o0 = __float2bfloat16(acc0[r] * s);
        __hip_bfloat16 o1 = __float2bfloat16(acc1[r] * s);
        Gout[(size_t)row * TOTF + col0]      = *(unsigned short*)&o0;
        Gout[(size_t)row * TOTF + col0 + 16] = *(unsigned short*)&o1;
    }
}

// ---------------- SpMM F=128: half-wave per neighbor, uint2 gathers, tight CSR ----------------
__global__ __launch_bounds__(256) void k_spmm128(const uint2* __restrict__ G2,
                                                 const int* __restrict__ rp,
                                                 const int* __restrict__ cols,
                                                 const float* __restrict__ bias,
                                                 uint2* __restrict__ H2) {
    const int lane = threadIdx.x & 63;
    const int wave = threadIdx.x >> 6;
    const int v = blockIdx.x * 4 + wave;   // N_NODES % 4 == 0
    const int b0 = rp[v];
    const int deg = rp[v + 1] - b0;
    const int c = lane & 31;   // uint2 index within row (cols 4c..4c+3)
    const int h = lane >> 5;   // half-wave id
    float ax = 0.f, ay = 0.f, az = 0.f, aw = 0.f;
    for (int base = 0; base < deg; base += 64) {
        const int n = min(64, deg - base);
        const int mycol = (lane < n) ? cols[b0 + base + lane] : 0;
        const int n8 = n & ~7;
        for (int j = 0; j < n8; j += 8) {
            int s0 = __shfl(mycol, j + h);
            int s1 = __shfl(mycol, j + 2 + h);
            int s2 = __shfl(mycol, j + 4 + h);
            int s3 = __shfl(mycol, j + 6 + h);
            uint2 u0 = G2[(size_t)s0 * 32 + c];
            uint2 u1 = G2[(size_t)s1 * 32 + c];
            uint2 u2 = G2[(size_t)s2 * 32 + c];
            uint2 u3 = G2[(size_t)s3 * 32 + c];
            ax += (bl(u0.x) + bl(u1.x)) + (bl(u2.x) + bl(u3.x));
            ay += (bh(u0.x) + bh(u1.x)) + (bh(u2.x) + bh(u3.x));
            az += (bl(u0.y) + bl(u1.y)) + (bl(u2.y) + bl(u3.y));
            aw += (bh(u0.y) + bh(u1.y)) + (bh(u2.y) + bh(u3.y));
        }
        for (int j = n8; j < n; j += 2) {
            int idx = j + h;
            int sj = __shfl(mycol, min(idx, n - 1));
            if (idx < n) {
                uint2 u = G2[(size_t)sj * 32 + c];
                ax += bl(u.x); ay += bh(u.x); az += bl(u.y); aw += bh(u.y);
            }
        }
    }
    ax += __shfl_xor(ax, 32);
    ay += __shfl_xor(ay, 32);
    az += __shfl_xor(az, 32);
    aw += __shfl_xor(aw, 32);
    if (h == 0) {
        float r = rsqrtf((float)max(deg, 1));
        float4 b = *(const float4*)&bias[4 * c];
        __hip_bfloat162 p0 = __float22bfloat162_rn({fmaxf(fmaf(ax, r, b.x), 0.f),
                                                    fmaxf(fmaf(ay, r, b.y), 0.f)});
        __hip_bfloat162 p1 = __float22bfloat162_rn({fmaxf(fmaf(az, r, b.z), 0.f),
                                                    fmaxf(fmaf(aw, r, b.w), 0.f)});
        uint2 o;
        o.x = *(unsigned int*)&p0;
        o.y = *(unsigned int*)&p1;
        H2[(size_t)v * 32 + c] = o;
    }
}

// ---------------- SpMM F=64: quarter-wave per neighbor, uint2 gathers, tight CSR ----------------
__global__ __launch_bounds__(256) void k_spmm64(const uint2* __restrict__ G2,
                                                const int* __restrict__ rp,
                                                const int* __restrict__ cols,
                                                const float* __restrict__ bias,
                                                uint2* __restrict__ H2) {
    const int lane = threadIdx.x & 63;
    const int wave = threadIdx.x >> 6;
    const int v = blockIdx.x * 4 + wave;
    const int b0 = rp[v];
    const int deg = rp[v + 1] - b0;
    const int c = lane & 15;   // uint2 index within row
    const int h = lane >> 4;   // quarter-wave id
    float ax = 0.f, ay = 0.f, az = 0.f, aw = 0.f;
    for (int base = 0; base < deg; base += 64) {
        const int n = min(64, deg - base);
        const int mycol = (lane < n) ? cols[b0 + base + lane] : 0;
        const int n16 = n & ~15;
        for (int j = 0; j < n16; j += 16) {
            int s0 = __shfl(mycol, j + h);
            int s1 = __shfl(mycol, j + 4 + h);
            int s2 = __shfl(mycol, j + 8 + h);
            int s3 = __shfl(mycol, j + 12 + h);
            uint2 u0 = G2[(size_t)s0 * 16 + c];
            uint2 u1 = G2[(size_t)s1 * 16 + c];
            uint2 u2 = G2[(size_t)s2 * 16 + c];
            uint2 u3 = G2[(size_t)s3 * 16 + c];
            ax += (bl(u0.x) + bl(u1.x)) + (bl(u2.x) + bl(u3.x));
            ay += (bh(u0.x) + bh(u1.x)) + (bh(u2.x) + bh(u3.x));
            az += (bl(u0.y) + bl(u1.y)) + (bl(u2.y) + bl(u3.y));
            aw += (bh(u0.y) + bh(u1.y)) + (bh(u2.y) + bh(u3.y));
        }
        for (int j = n16; j < n; j += 4) {
            int idx = j + h;
            int sj = __shfl(mycol, min(idx, n - 1));
            if (idx < n) {
                uint2 u = G2[(size_t)sj * 16 + c];
                ax += bl(u.x); ay += bh(u.x); az += bl(u.y); aw += bh(u.y);
            }
        }
    }
    ax += __shfl_xor(ax, 16); ax += __shfl_xor(ax, 32);
    ay += __shfl_xor(ay, 16); ay += __shfl_xor(ay, 32);
    az += __shfl_xor(az, 16); az += __shfl_xor(az, 32);
    aw += __shfl_xor(aw, 16); aw += __shfl_xor(aw, 32);
    if (h == 0) {
        float r = rsqrtf((float)max(deg, 1));
        float4 b = *(const float4*)&bias[4 * c];
        __hip_bfloat162 p0 = __float22bfloat162_rn({fmaxf(fmaf(ax, r, b.x), 0.f),
                                                    fmaxf(fmaf(ay, r, b.y), 0.f)});
        __hip_bfloat162 p1 = __float22bfloat162_rn({fmaxf(fmaf(az, r, b.z), 0.f),
                                                    fmaxf(fmaf(aw, r, b.w), 0.f)});
        uint2 o;
        o.x = *(unsigned int*)&p0;
        o.y = *(unsigned int*)&p1;
        H2[(size_t)v * 16 + c] = o;
    }
}

// ---------------- fused pooling + MLP + softmax (block per graph; h2 bf16 row-major) ----------------
__global__ __launch_bounds__(256) void k_poolmlp(const unsigned short* __restrict__ h2,
                                                 const int* __restrict__ gid,
                                                 const float* __restrict__ fcW1,
                                                 const float* __restrict__ fcb1,
                                                 const float* __restrict__ fcW2,
                                                 const float* __restrict__ fcb2,
                                                 float* __restrict__ out) {
    __shared__ int se[2];
    __shared__ float part[4][64];
    __shared__ float p[64];
    __shared__ float z[10];
    __shared__ float l[10];
    __shared__ float red[2];
    const int g = blockIdx.x;
    const int tid = threadIdx.x;  // 256
    if (tid < 2) {
        int target = g + tid;  // lower_bound over sorted gid
        int lo = 0, hi = N_NODES;
        while (lo < hi) {
            int mid = (lo + hi) >> 1;
            if (gid[mid] < target) lo = mid + 1; else hi = mid;
        }
        se[tid] = lo;
    }
    __syncthreads();
    const int s = se[0], e = se[1];
    const int c = tid & 63;
    const int w = tid >> 6;
    float acc = 0.f;
    for (int v = s + w; v < e; v += 4)
        acc += __uint_as_float(((unsigned int)h2[(size_t)v * 64 + c]) << 16);
    part[w][c] = acc;
    __syncthreads();
    if (tid < 64) {
        float t = part[0][tid] + part[1][tid] + part[2][tid] + part[3][tid];
        p[tid] = t / (float)max(e - s, 1);
    }
    __syncthreads();
    if (tid < 10) {
        float a = fcb1[tid];
        for (int k = 0; k < 64; k++) a = fmaf(p[k], fcW1[k * 10 + tid], a);
        z[tid] = fmaxf(a, 0.f);
    }
    __syncthreads();
    if (tid < 10) {
        float a = fcb2[tid];
        for (int k = 0; k < 10; k++) a = fmaf(z[k], fcW2[k * 10 + tid], a);
        l[tid] = a;
    }
    __syncthreads();
    if (tid == 0) {
        float m = l[0];
        for (int i = 1; i < 10; i++) m = fmaxf(m, l[i]);
        float ssum = 0.f;
        for (int i = 0; i < 10; i++) ssum += expf(l[i] - m);
        red[0] = m;
        red[1] = ssum;
    }
    __syncthreads();
    if (tid < 10) out[g * 10 + tid] = expf(l[tid] - red[0]) / red[1];
}

// ---------------- host ----------------
extern "C" void kernel_launch(void* const* d_in, const int* in_sizes, int n_in,
                              void* d_out, int out_size, void* d_ws, size_t ws_size,
                              hipStream_t stream) {
    const float* feats = (const float*)d_in[0];
    const int* src = (const int*)d_in[1];
    const int* dst = (const int*)d_in[2];
    const int* gid = (const int*)d_in[3];
    const float* W1 = (const float*)d_in[4];
    const float* b1 = (const float*)d_in[5];
    const float* W2 = (const float*)d_in[6];
    const float* b2 = (const float*)d_in[7];
    const float* fcW1 = (const float*)d_in[8];
    const float* fcb1 = (const float*)d_in[9];
    const float* fcW2 = (const float*)d_in[10];
    const float* fcb2 = (const float*)d_in[11];
    float* out = (float*)d_out;

    char* w = (char*)d_ws;
    size_t off = 0;
    auto alloc = [&](size_t bytes) -> void* {
        void* p = w + off;
        off = (off + bytes + 255) & ~(size_t)255;
        return p;
    };
    int* cnt_out = (int*)alloc(N_NODES * 4);
    int* rp      = (int*)alloc((N_NODES + 1) * 4);
    int* cols    = (int*)alloc((size_t)N_EDGES * 4);                         // 6.4 MB tight CSR
    int* Pd      = (int*)alloc(NBUCK * SBLK * 4);                            // 400 KB
    int* Ps      = (int*)alloc(NBUCK * SBLK * 4);
    int* Td      = (int*)alloc(NBUCK * 4);
    int* Ts      = (int*)alloc(NBUCK * 4);
    int* Bd      = (int*)alloc((NBUCK + 1) * 4);
    int* Bs      = (int*)alloc((NBUCK + 1) * 4);
    unsigned int* pb  = (unsigned int*)alloc((size_t)N_EDGES * 4);           // 6.4 MB packed
    unsigned char* sb = (unsigned char*)alloc((size_t)N_EDGES);              // 1.6 MB
    unsigned short* Wt1 = (unsigned short*)alloc(128 * 128 * 2);
    unsigned short* Wt2 = (unsigned short*)alloc(64 * 128 * 2);
    unsigned short* g1 = (unsigned short*)alloc((size_t)N_NODES * 128 * 2);  // bf16 row-major
    unsigned short* h1 = (unsigned short*)alloc((size_t)N_NODES * 128 * 2);  // bf16 row-major
    unsigned short* g2 = (unsigned short*)alloc((size_t)N_NODES * 64 * 2);   // bf16 row-major
    unsigned short* h2 = (unsigned short*)alloc((size_t)N_NODES * 64 * 2);   // bf16 row-major

    // build pipeline (bucket sort; no scattered device atomics, no memsets)
    k_hist2<<<SBLK + NB_PREP, 1024, 0, stream>>>(src, dst, Pd, Ps, W1, W2, Wt1, Wt2);
    k_scanA<<<2 * NBUCK, 128, 0, stream>>>(Pd, Ps, Td, Ts);
    k_scanB<<<1, 1024, 0, stream>>>(Td, Ts, Bd, Bs);
    k_scatter<<<2 * SBLK, 1024, 0, stream>>>(src, dst, Pd, Ps, Bd, Bs, pb, sb);
    k_finalize<<<NBUCK, 256, 0, stream>>>(pb, Bd, sb, Bs, rp, cnt_out, cols);

    // layer 1
    k_gemm_mfma<128, false><<<dim3(N_NODES / 32, 2), 256, 0, stream>>>(feats, Wt1, cnt_out, g1);
    k_spmm128<<<N_NODES / 4, 256, 0, stream>>>((const uint2*)g1, rp, cols, b1, (uint2*)h1);

    // layer 2
    k_gemm_mfma<64, true><<<dim3(N_NODES / 32, 1), 256, 0, stream>>>(h1, Wt2, cnt_out, g2);
    k_spmm64<<<N_NODES / 4, 256, 0, stream>>>((const uint2*)g2, rp, cols, b2, (uint2*)h2);

    k_poolmlp<<<N_GRAPHS, 256, 0, stream>>>(h2, gid, fcW1, fcb1, fcW2, fcb2, out);
}

// Round 11
// 336.744 us; speedup vs baseline: 1.7723x; 1.0443x over previous
//
#include <hip/hip_runtime.h>
#include <hip/hip_bf16.h>

#define N_NODES 100000
#define N_EDGES 1600000
#define N_GRAPHS 128
#define IN_F 128
#define H_F 128
#define OUT_F 64
#define HID 10
#define NCLS 10
#define XPAD 136    // LDS row stride in bf16 (pad 128 -> 136: 16-way conflict -> free 2-way)
#define BSH 7                     // bucket = node >> 7 (128-node windows)
#define NBUCK 782                 // ceil(100000/128)
#define SBLK 128                  // edge partitions for hist/scatter
#define EPB (N_EDGES / SBLK)      // 12500, exact
#define NB_PREP 4

typedef __attribute__((ext_vector_type(8))) short bf16x8;
typedef __attribute__((ext_vector_type(4))) float f32x4;
typedef __attribute__((ext_vector_type(2))) float f32x2;

__device__ __forceinline__ float bl(unsigned int u) { return __uint_as_float(u << 16); }
__device__ __forceinline__ float bh(unsigned int u) { return __uint_as_float(u & 0xffff0000u); }

// ---------------- phase 1: LDS-privatized bucket histograms (dst & src) + weight prep ----------------
__global__ __launch_bounds__(1024) void k_hist2(const int* __restrict__ src, const int* __restrict__ dst,
                                                int* __restrict__ Pd, int* __restrict__ Ps,
                                                const float* __restrict__ W1, const float* __restrict__ W2,
                                                unsigned short* __restrict__ Wt1, unsigned short* __restrict__ Wt2) {
    __shared__ int hd[NBUCK];
    __shared__ int hs[NBUCK];
    const int blk = blockIdx.x;
    if (blk < SBLK) {
        for (int i = threadIdx.x; i < NBUCK; i += 1024) { hd[i] = 0; hs[i] = 0; }
        __syncthreads();
        const int base = blk * EPB;
        for (int i = threadIdx.x; i < EPB; i += 1024) {
            atomicAdd(&hd[dst[base + i] >> BSH], 1);
            atomicAdd(&hs[src[base + i] >> BSH], 1);
        }
        __syncthreads();
        for (int b = threadIdx.x; b < NBUCK; b += 1024) {
            Pd[b * SBLK + blk] = hd[b];
            Ps[b * SBLK + blk] = hs[b];
        }
    } else {
        int t = (blk - SBLK) * 1024 + threadIdx.x;
        const int stride = NB_PREP * 1024;
        for (int i = t; i < 128 * 128; i += stride) {
            int c = i >> 7, k = i & 127;
            __hip_bfloat16 v = __float2bfloat16(W1[k * 128 + c]);
            Wt1[i] = *(unsigned short*)&v;
        }
        for (int i = t; i < 64 * 128; i += stride) {
            int c = i >> 7, k = i & 127;
            __hip_bfloat16 v = __float2bfloat16(W2[k * 64 + c]);
            Wt2[i] = *(unsigned short*)&v;
        }
    }
}

// ---------------- phase 2a: per-bucket scan across blocks (exclusive), emit totals ----------------
__global__ __launch_bounds__(128) void k_scanA(int* __restrict__ Pd, int* __restrict__ Ps,
                                               int* __restrict__ Td, int* __restrict__ Ts) {
    __shared__ int sc[128];
    const int b = blockIdx.x;
    const int t = threadIdx.x;
    int* P = (b < NBUCK) ? Pd : Ps;
    int* T = (b < NBUCK) ? Td : Ts;
    const int bb = (b < NBUCK) ? b : b - NBUCK;
    int v = P[bb * SBLK + t];
    sc[t] = v;
    __syncthreads();
    for (int off = 1; off < 128; off <<= 1) {
        int u = (t >= off) ? sc[t - off] : 0;
        __syncthreads();
        sc[t] += u;
        __syncthreads();
    }
    P[bb * SBLK + t] = sc[t] - v;    // exclusive within bucket
    if (t == 127) T[bb] = sc[127];
}

// ---------------- phase 2b: scan bucket totals -> global bases (with total at [NBUCK]) ----------------
__global__ __launch_bounds__(1024) void k_scanB(const int* __restrict__ Td, const int* __restrict__ Ts,
                                                int* __restrict__ Bd, int* __restrict__ Bs) {
    __shared__ int sc[1024];
    const int t = threadIdx.x;
    int v = (t < NBUCK) ? Td[t] : 0;
    sc[t] = v;
    __syncthreads();
    for (int off = 1; off < 1024; off <<= 1) {
        int u = (t >= off) ? sc[t - off] : 0;
        __syncthreads();
        sc[t] += u;
        __syncthreads();
    }
    if (t < NBUCK) Bd[t] = sc[t] - v;
    if (t == NBUCK - 1) Bd[NBUCK] = sc[t];
    __syncthreads();
    int v2 = (t < NBUCK) ? Ts[t] : 0;
    sc[t] = v2;
    __syncthreads();
    for (int off = 1; off < 1024; off <<= 1) {
        int u = (t >= off) ? sc[t - off] : 0;
        __syncthreads();
        sc[t] += u;
        __syncthreads();
    }
    if (t < NBUCK) Bs[t] = sc[t] - v2;
    if (t == NBUCK - 1) Bs[NBUCK] = sc[t];
}

// ---------------- phase 3: bucketed scatter, role-split, packed payloads ----------------
__global__ __launch_bounds__(1024) void k_scatter(const int* __restrict__ src, const int* __restrict__ dst,
                                                  const int* __restrict__ Pd, const int* __restrict__ Ps,
                                                  const int* __restrict__ Bd, const int* __restrict__ Bs,
                                                  unsigned int* __restrict__ pb, unsigned char* __restrict__ sb) {
    __shared__ int tk[NBUCK];
    const int b = blockIdx.x;
    const bool isPb = b < SBLK;
    const int blk = isPb ? b : b - SBLK;
    for (int i = threadIdx.x; i < NBUCK; i += 1024) tk[i] = 0;
    __syncthreads();
    const int base = blk * EPB;
    if (isPb) {
        for (int i = threadIdx.x; i < EPB; i += 1024) {
            int d = dst[base + i];
            int s = src[base + i];
            int bd = d >> BSH;
            int t = atomicAdd(&tk[bd], 1);
            pb[Bd[bd] + Pd[bd * SBLK + blk] + t] = ((unsigned)s << 7) | (unsigned)(d & 127);
        }
    } else {
        for (int i = threadIdx.x; i < EPB; i += 1024) {
            int s = src[base + i];
            int bs = s >> BSH;
            int t = atomicAdd(&tk[bs], 1);
            sb[Bs[bs] + Ps[bs * SBLK + blk] + t] = (unsigned char)(s & 127);
        }
    }
}

// ---------------- phase 4: tight CSR (cols+rp) + cnt_out per 128-node bucket ----------------
__global__ __launch_bounds__(256) void k_finalize(const unsigned int* __restrict__ pb, const int* __restrict__ Bd,
                                                  const unsigned char* __restrict__ sb, const int* __restrict__ Bs,
                                                  int* __restrict__ rp, int* __restrict__ cnt_out,
                                                  int* __restrict__ cols) {
    __shared__ int cnt[128];
    __shared__ int exc[128];
    __shared__ int tick[128];
    __shared__ int h[128];
    __shared__ int sc[128];
    const int b = blockIdx.x;
    const int tid = threadIdx.x;
    if (tid < 128) { cnt[tid] = 0; tick[tid] = 0; h[tid] = 0; }
    __syncthreads();
    const int e0 = Bd[b], e1 = Bd[b + 1];
    for (int i = e0 + tid; i < e1; i += 256) atomicAdd(&cnt[pb[i] & 127], 1);
    const int f0 = Bs[b], f1 = Bs[b + 1];
    for (int i = f0 + tid; i < f1; i += 256) atomicAdd(&h[sb[i]], 1);
    __syncthreads();
    if (tid < 128) sc[tid] = cnt[tid];
    __syncthreads();
    for (int off = 1; off < 128; off <<= 1) {
        int u = (tid < 128 && tid >= off) ? sc[tid - off] : 0;
        __syncthreads();
        if (tid < 128) sc[tid] += u;
        __syncthreads();
    }
    if (tid < 128) exc[tid] = sc[tid] - cnt[tid];
    __syncthreads();
    const int node0 = b << BSH;
    if (tid < 128 && node0 + tid < N_NODES) {
        rp[node0 + tid] = e0 + exc[tid];
        cnt_out[node0 + tid] = h[tid];
    }
    if (b == NBUCK - 1 && tid == 0) rp[N_NODES] = N_EDGES;
    for (int i = e0 + tid; i < e1; i += 256) {
        unsigned int p = pb[i];
        int loc = p & 127;
        int t = atomicAdd(&tick[loc], 1);
        cols[e0 + exc[loc] + t] = (int)(p >> 7);
    }
}

// ---------------- MFMA GEMM: G[v, cbase..+63] = rsqrt(deg_out[v]) * (X[v,:] @ W[:, cbase..+63])
// OUT_FP8: packed e4m3 bytes, row stride TOTF bytes. Else bf16, row stride TOTF elems.
// X: f32 (XBF16=false) or bf16 (XBF16=true), row stride 128.
template <int TOTF, bool XBF16, bool OUT_FP8>
__global__ __launch_bounds__(256) void k_gemm_mfma(const void* __restrict__ Xv,
                                                   const unsigned short* __restrict__ Wt,
                                                   const int* __restrict__ cnt_out,
                                                   void* __restrict__ GoutV) {
    __shared__ __align__(16) unsigned short Xs[32 * XPAD];
    __shared__ __align__(16) unsigned short Ws[64 * XPAD];
    const int tid = threadIdx.x;
    const int cbase = blockIdx.y * 64;
    const int row0 = blockIdx.x * 32;  // N_NODES % 32 == 0

    if constexpr (XBF16) {
        const uint2* X2 = (const uint2*)Xv;  // row = 32 uint2 (128 bf16)
#pragma unroll
        for (int j = 0; j < 4; j++) {
            int i = tid + 256 * j;
            int r = i >> 5, kk = i & 31;
            uint2 u = X2[(size_t)(row0 + r) * 32 + kk];
            *(uint2*)&Xs[r * XPAD + kk * 4] = u;
        }
    } else {
        const float4* X4 = (const float4*)Xv;  // row = 32 float4
#pragma unroll
        for (int j = 0; j < 4; j++) {
            int i = tid + 256 * j;
            int r = i >> 5, k4 = i & 31;
            float4 x = X4[(size_t)(row0 + r) * 32 + k4];
            __hip_bfloat162 lo = __float22bfloat162_rn({x.x, x.y});
            __hip_bfloat162 hi = __float22bfloat162_rn({x.z, x.w});
            uint2 u;
            u.x = *(unsigned int*)&lo;
            u.y = *(unsigned int*)&hi;
            *(uint2*)&Xs[r * XPAD + k4 * 4] = u;
        }
    }
    {
        const uint2* W2 = (const uint2*)Wt;  // row = 32 uint2
#pragma unroll
        for (int j = 0; j < 8; j++) {
            int i = tid + 256 * j;
            int c = i >> 5, kk = i & 31;
            uint2 u = W2[(size_t)(cbase + c) * 32 + kk];
            *(uint2*)&Ws[c * XPAD + kk * 4] = u;
        }
    }
    __syncthreads();

    const int lane = tid & 63;
    const int wv = tid >> 6;
    const int m = lane & 15;
    const int q = lane >> 4;
    const int roff = (wv & 1) * 16;
    const int coff = (wv >> 1) * 32;

    f32x4 acc0 = {0.f, 0.f, 0.f, 0.f}, acc1 = {0.f, 0.f, 0.f, 0.f};
#pragma unroll
    for (int ks = 0; ks < 4; ks++) {
        int kb = ks * 32 + q * 8;
        bf16x8 a  = *(const bf16x8*)&Xs[(roff + m) * XPAD + kb];
        bf16x8 b0 = *(const bf16x8*)&Ws[(coff + m) * XPAD + kb];
        bf16x8 b1 = *(const bf16x8*)&Ws[(coff + 16 + m) * XPAD + kb];
        acc0 = __builtin_amdgcn_mfma_f32_16x16x32_bf16(a, b0, acc0, 0, 0, 0);
        acc1 = __builtin_amdgcn_mfma_f32_16x16x32_bf16(a, b1, acc1, 0, 0, 0);
    }
#pragma unroll
    for (int r = 0; r < 4; r++) {
        int row = row0 + roff + q * 4 + r;
        float s = rsqrtf((float)max(cnt_out[row], 1));
        int col0 = cbase + coff + m;
        if constexpr (OUT_FP8) {
            unsigned int pk = __builtin_amdgcn_cvt_pk_fp8_f32(acc0[r] * s, acc1[r] * s, 0, false);
            unsigned char* gp = (unsigned char*)GoutV + (size_t)row * TOTF + col0;
            gp[0]  = (unsigned char)(pk & 0xffu);
            gp[16] = (unsigned char)((pk >> 8) & 0xffu);
        } else {
            unsigned short* Gout = (unsigned short*)GoutV;
            __hip_bfloat16 o0 = __float2bfloat16(acc0[r] * s);
            __hip_bfloat16 o1 = __float2bfloat16(acc1[r] * s);
            Gout[(size_t)row * TOTF + col0]      = *(unsigned short*)&o0;
            Gout[(size_t)row * TOTF + col0 + 16] = *(unsigned short*)&o1;
        }
    }
}

// ---------------- SpMM F=128, fp8 input: half-wave per neighbor, dword gathers, tight CSR ----------------
// G row = 128 fp8 = 128 B = 32 uints; lane c (0..31) covers cols 4c..4c+3. Output h1 bf16 row-major.
__global__ __launch_bounds__(256) void k_spmm128f8(const unsigned int* __restrict__ G,
                                                   const int* __restrict__ rp,
                                                   const int* __restrict__ cols,
                                                   const float* __restrict__ bias,
                                                   uint2* __restrict__ H2) {
    const int lane = threadIdx.x & 63;
    const int wave = threadIdx.x >> 6;
    const int v = blockIdx.x * 4 + wave;   // N_NODES % 4 == 0
    const int b0 = rp[v];
    const int deg = rp[v + 1] - b0;
    const int c = lane & 31;   // uint index within row (cols 4c..4c+3)
    const int h = lane >> 5;   // half-wave id
    float ax = 0.f, ay = 0.f, az = 0.f, aw = 0.f;
    for (int base = 0; base < deg; base += 64) {
        const int n = min(64, deg - base);
        const int mycol = (lane < n) ? cols[b0 + base + lane] : 0;
        const int n8 = n & ~7;
        for (int j = 0; j < n8; j += 8) {
            int s0 = __shfl(mycol, j + h);
            int s1 = __shfl(mycol, j + 2 + h);
            int s2 = __shfl(mycol, j + 4 + h);
            int s3 = __shfl(mycol, j + 6 + h);
            unsigned int u0 = G[(size_t)s0 * 32 + c];
            unsigned int u1 = G[(size_t)s1 * 32 + c];
            unsigned int u2 = G[(size_t)s2 * 32 + c];
            unsigned int u3 = G[(size_t)s3 * 32 + c];
            f32x2 l0 = __builtin_amdgcn_cvt_pk_f32_fp8(u0, false);
            f32x2 h0 = __builtin_amdgcn_cvt_pk_f32_fp8(u0, true);
            f32x2 l1 = __builtin_amdgcn_cvt_pk_f32_fp8(u1, false);
            f32x2 h1v = __builtin_amdgcn_cvt_pk_f32_fp8(u1, true);
            f32x2 l2 = __builtin_amdgcn_cvt_pk_f32_fp8(u2, false);
            f32x2 h2v = __builtin_amdgcn_cvt_pk_f32_fp8(u2, true);
            f32x2 l3 = __builtin_amdgcn_cvt_pk_f32_fp8(u3, false);
            f32x2 h3 = __builtin_amdgcn_cvt_pk_f32_fp8(u3, true);
            ax += (l0.x + l1.x) + (l2.x + l3.x);
            ay += (l0.y + l1.y) + (l2.y + l3.y);
            az += (h0.x + h1v.x) + (h2v.x + h3.x);
            aw += (h0.y + h1v.y) + (h2v.y + h3.y);
        }
        for (int j = n8; j < n; j += 2) {
            int idx = j + h;
            int sj = __shfl(mycol, min(idx, n - 1));
            if (idx < n) {
                unsigned int u = G[(size_t)sj * 32 + c];
                f32x2 lo = __builtin_amdgcn_cvt_pk_f32_fp8(u, false);
                f32x2 hi = __builtin_amdgcn_cvt_pk_f32_fp8(u, true);
                ax += lo.x; ay += lo.y; az += hi.x; aw += hi.y;
            }
        }
    }
    ax += __shfl_xor(ax, 32);
    ay += __shfl_xor(ay, 32);
    az += __shfl_xor(az, 32);
    aw += __shfl_xor(aw, 32);
    if (h == 0) {
        float r = rsqrtf((float)max(deg, 1));
        float4 b = *(const float4*)&bias[4 * c];
        __hip_bfloat162 p0 = __float22bfloat162_rn({fmaxf(fmaf(ax, r, b.x), 0.f),
                                                    fmaxf(fmaf(ay, r, b.y), 0.f)});
        __hip_bfloat162 p1 = __float22bfloat162_rn({fmaxf(fmaf(az, r, b.z), 0.f),
                                                    fmaxf(fmaf(aw, r, b.w), 0.f)});
        uint2 o;
        o.x = *(unsigned int*)&p0;
        o.y = *(unsigned int*)&p1;
        H2[(size_t)v * 32 + c] = o;
    }
}

// ---------------- SpMM F=64 (bf16 input): quarter-wave per neighbor, uint2 gathers, tight CSR ----------------
__global__ __launch_bounds__(256) void k_spmm64(const uint2* __restrict__ G2,
                                                const int* __restrict__ rp,
                                                const int* __restrict__ cols,
                                                const float* __restrict__ bias,
                                                uint2* __restrict__ H2) {
    const int lane = threadIdx.x & 63;
    const int wave = threadIdx.x >> 6;
    const int v = blockIdx.x * 4 + wave;
    const int b0 = rp[v];
    const int deg = rp[v + 1] - b0;
    const int c = lane & 15;   // uint2 index within row
    const int h = lane >> 4;   // quarter-wave id
    float ax = 0.f, ay = 0.f, az = 0.f, aw = 0.f;
    for (int base = 0; base < deg; base += 64) {
        const int n = min(64, deg - base);
        const int mycol = (lane < n) ? cols[b0 + base + lane] : 0;
        const int n16 = n & ~15;
        for (int j = 0; j < n16; j += 16) {
            int s0 = __shfl(mycol, j + h);
            int s1 = __shfl(mycol, j + 4 + h);
            int s2 = __shfl(mycol, j + 8 + h);
            int s3 = __shfl(mycol, j + 12 + h);
            uint2 u0 = G2[(size_t)s0 * 16 + c];
            uint2 u1 = G2[(size_t)s1 * 16 + c];
            uint2 u2 = G2[(size_t)s2 * 16 + c];
            uint2 u3 = G2[(size_t)s3 * 16 + c];
            ax += (bl(u0.x) + bl(u1.x)) + (bl(u2.x) + bl(u3.x));
            ay += (bh(u0.x) + bh(u1.x)) + (bh(u2.x) + bh(u3.x));
            az += (bl(u0.y) + bl(u1.y)) + (bl(u2.y) + bl(u3.y));
            aw += (bh(u0.y) + bh(u1.y)) + (bh(u2.y) + bh(u3.y));
        }
        for (int j = n16; j < n; j += 4) {
            int idx = j + h;
            int sj = __shfl(mycol, min(idx, n - 1));
            if (idx < n) {
                uint2 u = G2[(size_t)sj * 16 + c];
                ax += bl(u.x); ay += bh(u.x); az += bl(u.y); aw += bh(u.y);
            }
        }
    }
    ax += __shfl_xor(ax, 16); ax += __shfl_xor(ax, 32);
    ay += __shfl_xor(ay, 16); ay += __shfl_xor(ay, 32);
    az += __shfl_xor(az, 16); az += __shfl_xor(az, 32);
    aw += __shfl_xor(aw, 16); aw += __shfl_xor(aw, 32);
    if (h == 0) {
        float r = rsqrtf((float)max(deg, 1));
        float4 b = *(const float4*)&bias[4 * c];
        __hip_bfloat162 p0 = __float22bfloat162_rn({fmaxf(fmaf(ax, r, b.x), 0.f),
                                                    fmaxf(fmaf(ay, r, b.y), 0.f)});
        __hip_bfloat162 p1 = __float22bfloat162_rn({fmaxf(fmaf(az, r, b.z), 0.f),
                                                    fmaxf(fmaf(aw, r, b.w), 0.f)});
        uint2 o;
        o.x = *(unsigned int*)&p0;
        o.y = *(unsigned int*)&p1;
        H2[(size_t)v * 16 + c] = o;
    }
}

// ---------------- fused pooling + MLP + softmax (block per graph; h2 bf16 row-major) ----------------
__global__ __launch_bounds__(256) void k_poolmlp(const unsigned short* __restrict__ h2,
                                                 const int* __restrict__ gid,
                                                 const float* __restrict__ fcW1,
                                                 const float* __restrict__ fcb1,
                                                 const float* __restrict__ fcW2,
                                                 const float* __restrict__ fcb2,
                                                 float* __restrict__ out) {
    __shared__ int se[2];
    __shared__ float part[4][64];
    __shared__ float p[64];
    __shared__ float z[10];
    __shared__ float l[10];
    __shared__ float red[2];
    const int g = blockIdx.x;
    const int tid = threadIdx.x;  // 256
    if (tid < 2) {
        int target = g + tid;  // lower_bound over sorted gid
        int lo = 0, hi = N_NODES;
        while (lo < hi) {
            int mid = (lo + hi) >> 1;
            if (gid[mid] < target) lo = mid + 1; else hi = mid;
        }
        se[tid] = lo;
    }
    __syncthreads();
    const int s = se[0], e = se[1];
    const int c = tid & 63;
    const int w = tid >> 6;
    float acc = 0.f;
    for (int v = s + w; v < e; v += 4)
        acc += __uint_as_float(((unsigned int)h2[(size_t)v * 64 + c]) << 16);
    part[w][c] = acc;
    __syncthreads();
    if (tid < 64) {
        float t = part[0][tid] + part[1][tid] + part[2][tid] + part[3][tid];
        p[tid] = t / (float)max(e - s, 1);
    }
    __syncthreads();
    if (tid < 10) {
        float a = fcb1[tid];
        for (int k = 0; k < 64; k++) a = fmaf(p[k], fcW1[k * 10 + tid], a);
        z[tid] = fmaxf(a, 0.f);
    }
    __syncthreads();
    if (tid < 10) {
        float a = fcb2[tid];
        for (int k = 0; k < 10; k++) a = fmaf(z[k], fcW2[k * 10 + tid], a);
        l[tid] = a;
    }
    __syncthreads();
    if (tid == 0) {
        float m = l[0];
        for (int i = 1; i < 10; i++) m = fmaxf(m, l[i]);
        float ssum = 0.f;
        for (int i = 0; i < 10; i++) ssum += expf(l[i] - m);
        red[0] = m;
        red[1] = ssum;
    }
    __syncthreads();
    if (tid < 10) out[g * 10 + tid] = expf(l[tid] - red[0]) / red[1];
}

// ---------------- host ----------------
extern "C" void kernel_launch(void* const* d_in, const int* in_sizes, int n_in,
                              void* d_out, int out_size, void* d_ws, size_t ws_size,
                              hipStream_t stream) {
    const float* feats = (const float*)d_in[0];
    const int* src = (const int*)d_in[1];
    const int* dst = (const int*)d_in[2];
    const int* gid = (const int*)d_in[3];
    const float* W1 = (const float*)d_in[4];
    const float* b1 = (const float*)d_in[5];
    const float* W2 = (const float*)d_in[6];
    const float* b2 = (const float*)d_in[7];
    const float* fcW1 = (const float*)d_in[8];
    const float* fcb1 = (const float*)d_in[9];
    const float* fcW2 = (const float*)d_in[10];
    const float* fcb2 = (const float*)d_in[11];
    float* out = (float*)d_out;

    char* w = (char*)d_ws;
    size_t off = 0;
    auto alloc = [&](size_t bytes) -> void* {
        void* p = w + off;
        off = (off + bytes + 255) & ~(size_t)255;
        return p;
    };
    int* cnt_out = (int*)alloc(N_NODES * 4);
    int* rp      = (int*)alloc((N_NODES + 1) * 4);
    int* cols    = (int*)alloc((size_t)N_EDGES * 4);                         // 6.4 MB tight CSR
    int* Pd      = (int*)alloc(NBUCK * SBLK * 4);                            // 400 KB
    int* Ps      = (int*)alloc(NBUCK * SBLK * 4);
    int* Td      = (int*)alloc(NBUCK * 4);
    int* Ts      = (int*)alloc(NBUCK * 4);
    int* Bd      = (int*)alloc((NBUCK + 1) * 4);
    int* Bs      = (int*)alloc((NBUCK + 1) * 4);
    unsigned int* pb  = (unsigned int*)alloc((size_t)N_EDGES * 4);           // 6.4 MB packed
    unsigned char* sb = (unsigned char*)alloc((size_t)N_EDGES);              // 1.6 MB
    unsigned short* Wt1 = (unsigned short*)alloc(128 * 128 * 2);
    unsigned short* Wt2 = (unsigned short*)alloc(64 * 128 * 2);
    unsigned char* g1 = (unsigned char*)alloc((size_t)N_NODES * 128);        // fp8 e4m3 [v][128], 12.8 MB
    unsigned short* h1 = (unsigned short*)alloc((size_t)N_NODES * 128 * 2);  // bf16 row-major
    unsigned short* g2 = (unsigned short*)alloc((size_t)N_NODES * 64 * 2);   // bf16 row-major
    unsigned short* h2 = (unsigned short*)alloc((size_t)N_NODES * 64 * 2);   // bf16 row-major

    // build pipeline (bucket sort; no scattered device atomics, no memsets)
    k_hist2<<<SBLK + NB_PREP, 1024, 0, stream>>>(src, dst, Pd, Ps, W1, W2, Wt1, Wt2);
    k_scanA<<<2 * NBUCK, 128, 0, stream>>>(Pd, Ps, Td, Ts);
    k_scanB<<<1, 1024, 0, stream>>>(Td, Ts, Bd, Bs);
    k_scatter<<<2 * SBLK, 1024, 0, stream>>>(src, dst, Pd, Ps, Bd, Bs, pb, sb);
    k_finalize<<<NBUCK, 256, 0, stream>>>(pb, Bd, sb, Bs, rp, cnt_out, cols);

    // layer 1 (g1 in fp8: halves the dominant gather traffic)
    k_gemm_mfma<128, false, true><<<dim3(N_NODES / 32, 2), 256, 0, stream>>>(feats, Wt1, cnt_out, g1);
    k_spmm128f8<<<N_NODES / 4, 256, 0, stream>>>((const unsigned int*)g1, rp, cols, b1, (uint2*)h1);

    // layer 2 (bf16)
    k_gemm_mfma<64, true, false><<<dim3(N_NODES / 32, 1), 256, 0, stream>>>(h1, Wt2, cnt_out, g2);
    k_spmm64<<<N_NODES / 4, 256, 0, stream>>>((const uint2*)g2, rp, cols, b2, (uint2*)h2);

    k_poolmlp<<<N_GRAPHS, 256, 0, stream>>>(h2, gid, fcW1, fcb1, fcW2, fcb2, out);
}

// Round 12
// 295.896 us; speedup vs baseline: 2.0170x; 1.1380x over previous
//
#include <hip/hip_runtime.h>
#include <hip/hip_bf16.h>

#define N_NODES 100000
#define N_EDGES 1600000
#define N_GRAPHS 128
#define IN_F 128
#define H_F 128
#define OUT_F 64
#define HID 10
#define NCLS 10
#define XPAD 136    // LDS row stride in bf16 (pad 128 -> 136: 16-way conflict -> free 2-way)
#define BSH 7                     // bucket = node >> 7 (128-node windows)
#define NBUCK 782                 // ceil(100000/128)
#define SBLK 128                  // edge partitions for hist/scatter
#define EPB (N_EDGES / SBLK)      // 12500, exact
#define NB_PREP 4
#define PCHUNK 8                  // pooling partials per graph

typedef __attribute__((ext_vector_type(8))) short bf16x8;
typedef __attribute__((ext_vector_type(4))) float f32x4;
typedef __attribute__((ext_vector_type(2))) float f32x2;

__device__ __forceinline__ float bl(unsigned int u) { return __uint_as_float(u << 16); }
__device__ __forceinline__ float bh(unsigned int u) { return __uint_as_float(u & 0xffff0000u); }

// ---------------- phase 1: LDS-privatized bucket histograms (dst & src) + weight prep ----------------
__global__ __launch_bounds__(1024) void k_hist2(const int* __restrict__ src, const int* __restrict__ dst,
                                                int* __restrict__ Pd, int* __restrict__ Ps,
                                                const float* __restrict__ W1, const float* __restrict__ W2,
                                                unsigned short* __restrict__ Wt1, unsigned short* __restrict__ Wt2) {
    __shared__ int hd[NBUCK];
    __shared__ int hs[NBUCK];
    const int blk = blockIdx.x;
    if (blk < SBLK) {
        for (int i = threadIdx.x; i < NBUCK; i += 1024) { hd[i] = 0; hs[i] = 0; }
        __syncthreads();
        const int base = blk * EPB;
        for (int i = threadIdx.x; i < EPB; i += 1024) {
            atomicAdd(&hd[dst[base + i] >> BSH], 1);
            atomicAdd(&hs[src[base + i] >> BSH], 1);
        }
        __syncthreads();
        for (int b = threadIdx.x; b < NBUCK; b += 1024) {
            Pd[b * SBLK + blk] = hd[b];
            Ps[b * SBLK + blk] = hs[b];
        }
    } else {
        int t = (blk - SBLK) * 1024 + threadIdx.x;
        const int stride = NB_PREP * 1024;
        for (int i = t; i < 128 * 128; i += stride) {
            int c = i >> 7, k = i & 127;
            __hip_bfloat16 v = __float2bfloat16(W1[k * 128 + c]);
            Wt1[i] = *(unsigned short*)&v;
        }
        for (int i = t; i < 64 * 128; i += stride) {
            int c = i >> 7, k = i & 127;
            __hip_bfloat16 v = __float2bfloat16(W2[k * 64 + c]);
            Wt2[i] = *(unsigned short*)&v;
        }
    }
}

// ---------------- phase 2a: per-bucket scan across blocks (exclusive), emit totals ----------------
__global__ __launch_bounds__(128) void k_scanA(int* __restrict__ Pd, int* __restrict__ Ps,
                                               int* __restrict__ Td, int* __restrict__ Ts) {
    __shared__ int sc[128];
    const int b = blockIdx.x;
    const int t = threadIdx.x;
    int* P = (b < NBUCK) ? Pd : Ps;
    int* T = (b < NBUCK) ? Td : Ts;
    const int bb = (b < NBUCK) ? b : b - NBUCK;
    int v = P[bb * SBLK + t];
    sc[t] = v;
    __syncthreads();
    for (int off = 1; off < 128; off <<= 1) {
        int u = (t >= off) ? sc[t - off] : 0;
        __syncthreads();
        sc[t] += u;
        __syncthreads();
    }
    P[bb * SBLK + t] = sc[t] - v;    // exclusive within bucket
    if (t == 127) T[bb] = sc[127];
}

// ---------------- phase 2b: scan bucket totals -> global bases (with total at [NBUCK]) ----------------
__global__ __launch_bounds__(1024) void k_scanB(const int* __restrict__ Td, const int* __restrict__ Ts,
                                                int* __restrict__ Bd, int* __restrict__ Bs) {
    __shared__ int sc[1024];
    const int t = threadIdx.x;
    int v = (t < NBUCK) ? Td[t] : 0;
    sc[t] = v;
    __syncthreads();
    for (int off = 1; off < 1024; off <<= 1) {
        int u = (t >= off) ? sc[t - off] : 0;
        __syncthreads();
        sc[t] += u;
        __syncthreads();
    }
    if (t < NBUCK) Bd[t] = sc[t] - v;
    if (t == NBUCK - 1) Bd[NBUCK] = sc[t];
    __syncthreads();
    int v2 = (t < NBUCK) ? Ts[t] : 0;
    sc[t] = v2;
    __syncthreads();
    for (int off = 1; off < 1024; off <<= 1) {
        int u = (t >= off) ? sc[t - off] : 0;
        __syncthreads();
        sc[t] += u;
        __syncthreads();
    }
    if (t < NBUCK) Bs[t] = sc[t] - v2;
    if (t == NBUCK - 1) Bs[NBUCK] = sc[t];
}

// ---------------- phase 3: bucketed scatter, role-split, packed payloads ----------------
__global__ __launch_bounds__(1024) void k_scatter(const int* __restrict__ src, const int* __restrict__ dst,
                                                  const int* __restrict__ Pd, const int* __restrict__ Ps,
                                                  const int* __restrict__ Bd, const int* __restrict__ Bs,
                                                  unsigned int* __restrict__ pb, unsigned char* __restrict__ sb) {
    __shared__ int tk[NBUCK];
    const int b = blockIdx.x;
    const bool isPb = b < SBLK;
    const int blk = isPb ? b : b - SBLK;
    for (int i = threadIdx.x; i < NBUCK; i += 1024) tk[i] = 0;
    __syncthreads();
    const int base = blk * EPB;
    if (isPb) {
        for (int i = threadIdx.x; i < EPB; i += 1024) {
            int d = dst[base + i];
            int s = src[base + i];
            int bd = d >> BSH;
            int t = atomicAdd(&tk[bd], 1);
            pb[Bd[bd] + Pd[bd * SBLK + blk] + t] = ((unsigned)s << 7) | (unsigned)(d & 127);
        }
    } else {
        for (int i = threadIdx.x; i < EPB; i += 1024) {
            int s = src[base + i];
            int bs = s >> BSH;
            int t = atomicAdd(&tk[bs], 1);
            sb[Bs[bs] + Ps[bs * SBLK + blk] + t] = (unsigned char)(s & 127);
        }
    }
}

// ---------------- phase 4: tight CSR (cols+rp) + cnt_out per 128-node bucket ----------------
__global__ __launch_bounds__(256) void k_finalize(const unsigned int* __restrict__ pb, const int* __restrict__ Bd,
                                                  const unsigned char* __restrict__ sb, const int* __restrict__ Bs,
                                                  int* __restrict__ rp, int* __restrict__ cnt_out,
                                                  int* __restrict__ cols) {
    __shared__ int cnt[128];
    __shared__ int exc[128];
    __shared__ int tick[128];
    __shared__ int h[128];
    __shared__ int sc[128];
    const int b = blockIdx.x;
    const int tid = threadIdx.x;
    if (tid < 128) { cnt[tid] = 0; tick[tid] = 0; h[tid] = 0; }
    __syncthreads();
    const int e0 = Bd[b], e1 = Bd[b + 1];
    for (int i = e0 + tid; i < e1; i += 256) atomicAdd(&cnt[pb[i] & 127], 1);
    const int f0 = Bs[b], f1 = Bs[b + 1];
    for (int i = f0 + tid; i < f1; i += 256) atomicAdd(&h[sb[i]], 1);
    __syncthreads();
    if (tid < 128) sc[tid] = cnt[tid];
    __syncthreads();
    for (int off = 1; off < 128; off <<= 1) {
        int u = (tid < 128 && tid >= off) ? sc[tid - off] : 0;
        __syncthreads();
        if (tid < 128) sc[tid] += u;
        __syncthreads();
    }
    if (tid < 128) exc[tid] = sc[tid] - cnt[tid];
    __syncthreads();
    const int node0 = b << BSH;
    if (tid < 128 && node0 + tid < N_NODES) {
        rp[node0 + tid] = e0 + exc[tid];
        cnt_out[node0 + tid] = h[tid];
    }
    if (b == NBUCK - 1 && tid == 0) rp[N_NODES] = N_EDGES;
    for (int i = e0 + tid; i < e1; i += 256) {
        unsigned int p = pb[i];
        int loc = p & 127;
        int t = atomicAdd(&tick[loc], 1);
        cols[e0 + exc[loc] + t] = (int)(p >> 7);
    }
}

// ---------------- MFMA GEMM: G[v, cbase..+63] = rsqrt(deg_out[v]) * (X[v,:] @ W[:, cbase..+63])
// OUT_FP8: packed e4m3 bytes, row stride TOTF bytes. Else bf16, row stride TOTF elems.
template <int TOTF, bool XBF16, bool OUT_FP8>
__global__ __launch_bounds__(256) void k_gemm_mfma(const void* __restrict__ Xv,
                                                   const unsigned short* __restrict__ Wt,
                                                   const int* __restrict__ cnt_out,
                                                   void* __restrict__ GoutV) {
    __shared__ __align__(16) unsigned short Xs[32 * XPAD];
    __shared__ __align__(16) unsigned short Ws[64 * XPAD];
    const int tid = threadIdx.x;
    const int cbase = blockIdx.y * 64;
    const int row0 = blockIdx.x * 32;  // N_NODES % 32 == 0

    if constexpr (XBF16) {
        const uint2* X2 = (const uint2*)Xv;  // row = 32 uint2 (128 bf16)
#pragma unroll
        for (int j = 0; j < 4; j++) {
            int i = tid + 256 * j;
            int r = i >> 5, kk = i & 31;
            uint2 u = X2[(size_t)(row0 + r) * 32 + kk];
            *(uint2*)&Xs[r * XPAD + kk * 4] = u;
        }
    } else {
        const float4* X4 = (const float4*)Xv;  // row = 32 float4
#pragma unroll
        for (int j = 0; j < 4; j++) {
            int i = tid + 256 * j;
            int r = i >> 5, k4 = i & 31;
            float4 x = X4[(size_t)(row0 + r) * 32 + k4];
            __hip_bfloat162 lo = __float22bfloat162_rn({x.x, x.y});
            __hip_bfloat162 hi = __float22bfloat162_rn({x.z, x.w});
            uint2 u;
            u.x = *(unsigned int*)&lo;
            u.y = *(unsigned int*)&hi;
            *(uint2*)&Xs[r * XPAD + k4 * 4] = u;
        }
    }
    {
        const uint2* W2 = (const uint2*)Wt;  // row = 32 uint2
#pragma unroll
        for (int j = 0; j < 8; j++) {
            int i = tid + 256 * j;
            int c = i >> 5, kk = i & 31;
            uint2 u = W2[(size_t)(cbase + c) * 32 + kk];
            *(uint2*)&Ws[c * XPAD + kk * 4] = u;
        }
    }
    __syncthreads();

    const int lane = tid & 63;
    const int wv = tid >> 6;
    const int m = lane & 15;
    const int q = lane >> 4;
    const int roff = (wv & 1) * 16;
    const int coff = (wv >> 1) * 32;

    f32x4 acc0 = {0.f, 0.f, 0.f, 0.f}, acc1 = {0.f, 0.f, 0.f, 0.f};
#pragma unroll
    for (int ks = 0; ks < 4; ks++) {
        int kb = ks * 32 + q * 8;
        bf16x8 a  = *(const bf16x8*)&Xs[(roff + m) * XPAD + kb];
        bf16x8 b0 = *(const bf16x8*)&Ws[(coff + m) * XPAD + kb];
        bf16x8 b1 = *(const bf16x8*)&Ws[(coff + 16 + m) * XPAD + kb];
        acc0 = __builtin_amdgcn_mfma_f32_16x16x32_bf16(a, b0, acc0, 0, 0, 0);
        acc1 = __builtin_amdgcn_mfma_f32_16x16x32_bf16(a, b1, acc1, 0, 0, 0);
    }
#pragma unroll
    for (int r = 0; r < 4; r++) {
        int row = row0 + roff + q * 4 + r;
        float s = rsqrtf((float)max(cnt_out[row], 1));
        int col0 = cbase + coff + m;
        if constexpr (OUT_FP8) {
            unsigned int pk = __builtin_amdgcn_cvt_pk_fp8_f32(acc0[r] * s, acc1[r] * s, 0, false);
            unsigned char* gp = (unsigned char*)GoutV + (size_t)row * TOTF + col0;
            gp[0]  = (unsigned char)(pk & 0xffu);
            gp[16] = (unsigned char)((pk >> 8) & 0xffu);
        } else {
            unsigned short* Gout = (unsigned short*)GoutV;
            __hip_bfloat16 o0 = __float2bfloat16(acc0[r] * s);
            __hip_bfloat16 o1 = __float2bfloat16(acc1[r] * s);
            Gout[(size_t)row * TOTF + col0]      = *(unsigned short*)&o0;
            Gout[(size_t)row * TOTF + col0 + 16] = *(unsigned short*)&o1;
        }
    }
}

// ---------------- SpMM F=128, fp8 input: half-wave per neighbor, dword gathers, tight CSR ----------------
// G row = 128 fp8 = 128 B = 32 uints; lane c (0..31) covers cols 4c..4c+3. Output h1 bf16 row-major.
__global__ __launch_bounds__(256) void k_spmm128f8(const unsigned int* __restrict__ G,
                                                   const int* __restrict__ rp,
                                                   const int* __restrict__ cols,
                                                   const float* __restrict__ bias,
                                                   uint2* __restrict__ H2) {
    const int lane = threadIdx.x & 63;
    const int wave = threadIdx.x >> 6;
    const int v = blockIdx.x * 4 + wave;   // N_NODES % 4 == 0
    const int b0 = rp[v];
    const int deg = rp[v + 1] - b0;
    const int c = lane & 31;   // uint index within row (cols 4c..4c+3)
    const int h = lane >> 5;   // half-wave id
    float ax = 0.f, ay = 0.f, az = 0.f, aw = 0.f;
    for (int base = 0; base < deg; base += 64) {
        const int n = min(64, deg - base);
        const int mycol = (lane < n) ? cols[b0 + base + lane] : 0;
        const int n8 = n & ~7;
        for (int j = 0; j < n8; j += 8) {
            int s0 = __shfl(mycol, j + h);
            int s1 = __shfl(mycol, j + 2 + h);
            int s2 = __shfl(mycol, j + 4 + h);
            int s3 = __shfl(mycol, j + 6 + h);
            unsigned int u0 = G[(size_t)s0 * 32 + c];
            unsigned int u1 = G[(size_t)s1 * 32 + c];
            unsigned int u2 = G[(size_t)s2 * 32 + c];
            unsigned int u3 = G[(size_t)s3 * 32 + c];
            f32x2 l0 = __builtin_amdgcn_cvt_pk_f32_fp8(u0, false);
            f32x2 h0 = __builtin_amdgcn_cvt_pk_f32_fp8(u0, true);
            f32x2 l1 = __builtin_amdgcn_cvt_pk_f32_fp8(u1, false);
            f32x2 h1v = __builtin_amdgcn_cvt_pk_f32_fp8(u1, true);
            f32x2 l2 = __builtin_amdgcn_cvt_pk_f32_fp8(u2, false);
            f32x2 h2v = __builtin_amdgcn_cvt_pk_f32_fp8(u2, true);
            f32x2 l3 = __builtin_amdgcn_cvt_pk_f32_fp8(u3, false);
            f32x2 h3 = __builtin_amdgcn_cvt_pk_f32_fp8(u3, true);
            ax += (l0.x + l1.x) + (l2.x + l3.x);
            ay += (l0.y + l1.y) + (l2.y + l3.y);
            az += (h0.x + h1v.x) + (h2v.x + h3.x);
            aw += (h0.y + h1v.y) + (h2v.y + h3.y);
        }
        for (int j = n8; j < n; j += 2) {
            int idx = j + h;
            int sj = __shfl(mycol, min(idx, n - 1));
            if (idx < n) {
                unsigned int u = G[(size_t)sj * 32 + c];
                f32x2 lo = __builtin_amdgcn_cvt_pk_f32_fp8(u, false);
                f32x2 hi = __builtin_amdgcn_cvt_pk_f32_fp8(u, true);
                ax += lo.x; ay += lo.y; az += hi.x; aw += hi.y;
            }
        }
    }
    ax += __shfl_xor(ax, 32);
    ay += __shfl_xor(ay, 32);
    az += __shfl_xor(az, 32);
    aw += __shfl_xor(aw, 32);
    if (h == 0) {
        float r = rsqrtf((float)max(deg, 1));
        float4 b = *(const float4*)&bias[4 * c];
        __hip_bfloat162 p0 = __float22bfloat162_rn({fmaxf(fmaf(ax, r, b.x), 0.f),
                                                    fmaxf(fmaf(ay, r, b.y), 0.f)});
        __hip_bfloat162 p1 = __float22bfloat162_rn({fmaxf(fmaf(az, r, b.z), 0.f),
                                                    fmaxf(fmaf(aw, r, b.w), 0.f)});
        uint2 o;
        o.x = *(unsigned int*)&p0;
        o.y = *(unsigned int*)&p1;
        H2[(size_t)v * 32 + c] = o;
    }
}

// ---------------- SpMM F=64, fp8 input: quarter-wave per neighbor, dword gathers, tight CSR ----------------
// G row = 64 fp8 = 64 B = 16 uints; lane c (0..15) covers cols 4c..4c+3. Output h2 bf16 row-major.
__global__ __launch_bounds__(256) void k_spmm64f8(const unsigned int* __restrict__ G,
                                                  const int* __restrict__ rp,
                                                  const int* __restrict__ cols,
                                                  const float* __restrict__ bias,
                                                  uint2* __restrict__ H2) {
    const int lane = threadIdx.x & 63;
    const int wave = threadIdx.x >> 6;
    const int v = blockIdx.x * 4 + wave;
    const int b0 = rp[v];
    const int deg = rp[v + 1] - b0;
    const int c = lane & 15;   // uint index within row
    const int h = lane >> 4;   // quarter-wave id
    float ax = 0.f, ay = 0.f, az = 0.f, aw = 0.f;
    for (int base = 0; base < deg; base += 64) {
        const int n = min(64, deg - base);
        const int mycol = (lane < n) ? cols[b0 + base + lane] : 0;
        const int n16 = n & ~15;
        for (int j = 0; j < n16; j += 16) {
            int s0 = __shfl(mycol, j + h);
            int s1 = __shfl(mycol, j + 4 + h);
            int s2 = __shfl(mycol, j + 8 + h);
            int s3 = __shfl(mycol, j + 12 + h);
            unsigned int u0 = G[(size_t)s0 * 16 + c];
            unsigned int u1 = G[(size_t)s1 * 16 + c];
            unsigned int u2 = G[(size_t)s2 * 16 + c];
            unsigned int u3 = G[(size_t)s3 * 16 + c];
            f32x2 l0 = __builtin_amdgcn_cvt_pk_f32_fp8(u0, false);
            f32x2 h0 = __builtin_amdgcn_cvt_pk_f32_fp8(u0, true);
            f32x2 l1 = __builtin_amdgcn_cvt_pk_f32_fp8(u1, false);
            f32x2 h1v = __builtin_amdgcn_cvt_pk_f32_fp8(u1, true);
            f32x2 l2 = __builtin_amdgcn_cvt_pk_f32_fp8(u2, false);
            f32x2 h2v = __builtin_amdgcn_cvt_pk_f32_fp8(u2, true);
            f32x2 l3 = __builtin_amdgcn_cvt_pk_f32_fp8(u3, false);
            f32x2 h3 = __builtin_amdgcn_cvt_pk_f32_fp8(u3, true);
            ax += (l0.x + l1.x) + (l2.x + l3.x);
            ay += (l0.y + l1.y) + (l2.y + l3.y);
            az += (h0.x + h1v.x) + (h2v.x + h3.x);
            aw += (h0.y + h1v.y) + (h2v.y + h3.y);
        }
        for (int j = n16; j < n; j += 4) {
            int idx = j + h;
            int sj = __shfl(mycol, min(idx, n - 1));
            if (idx < n) {
                unsigned int u = G[(size_t)sj * 16 + c];
                f32x2 lo = __builtin_amdgcn_cvt_pk_f32_fp8(u, false);
                f32x2 hi = __builtin_amdgcn_cvt_pk_f32_fp8(u, true);
                ax += lo.x; ay += lo.y; az += hi.x; aw += hi.y;
            }
        }
    }
    ax += __shfl_xor(ax, 16); ax += __shfl_xor(ax, 32);
    ay += __shfl_xor(ay, 16); ay += __shfl_xor(ay, 32);
    az += __shfl_xor(az, 16); az += __shfl_xor(az, 32);
    aw += __shfl_xor(aw, 16); aw += __shfl_xor(aw, 32);
    if (h == 0) {
        float r = rsqrtf((float)max(deg, 1));
        float4 b = *(const float4*)&bias[4 * c];
        __hip_bfloat162 p0 = __float22bfloat162_rn({fmaxf(fmaf(ax, r, b.x), 0.f),
                                                    fmaxf(fmaf(ay, r, b.y), 0.f)});
        __hip_bfloat162 p1 = __float22bfloat162_rn({fmaxf(fmaf(az, r, b.z), 0.f),
                                                    fmaxf(fmaf(aw, r, b.w), 0.f)});
        uint2 o;
        o.x = *(unsigned int*)&p0;
        o.y = *(unsigned int*)&p1;
        H2[(size_t)v * 16 + c] = o;
    }
}

// ---------------- pooling stage 1: partial sums, 8 chunks per graph ----------------
// block (chunk=blockIdx.x, graph=blockIdx.y), 256 thr = 16 rows x 16 col-pairs (uint2)
__global__ __launch_bounds__(256) void k_pool(const unsigned short* __restrict__ h2,
                                              const int* __restrict__ gid,
                                              float* __restrict__ part) {
    __shared__ int se[2];
    __shared__ float red[16][16][4];
    const int cpart = blockIdx.x;
    const int g = blockIdx.y;
    const int tid = threadIdx.x;
    if (tid < 2) {
        int target = g + tid;  // lower_bound over sorted gid
        int lo = 0, hi = N_NODES;
        while (lo < hi) {
            int mid = (lo + hi) >> 1;
            if (gid[mid] < target) lo = mid + 1; else hi = mid;
        }
        se[tid] = lo;
    }
    __syncthreads();
    const int s = se[0], e = se[1];
    const int chunk = (e - s + PCHUNK - 1) / PCHUNK;
    const int lo = s + cpart * chunk;
    const int hi = min(lo + chunk, e);
    const int r = tid >> 4, cp = tid & 15;
    float a0 = 0.f, a1 = 0.f, a2 = 0.f, a3 = 0.f;
    const uint2* H = (const uint2*)h2;   // row = 16 uint2
    for (int v = lo + r; v < hi; v += 16) {
        uint2 u = H[(size_t)v * 16 + cp];
        a0 += bl(u.x); a1 += bh(u.x); a2 += bl(u.y); a3 += bh(u.y);
    }
    red[r][cp][0] = a0; red[r][cp][1] = a1; red[r][cp][2] = a2; red[r][cp][3] = a3;
    for (int off = 8; off > 0; off >>= 1) {
        __syncthreads();
        if (r < off) {
#pragma unroll
            for (int k = 0; k < 4; k++) red[r][cp][k] += red[r + off][cp][k];
        }
    }
    __syncthreads();
    if (r == 0) {
        float4 o = {red[0][cp][0], red[0][cp][1], red[0][cp][2], red[0][cp][3]};
        *(float4*)&part[((size_t)cpart * N_GRAPHS + g) * 64 + 4 * cp] = o;
    }
}

// ---------------- pooling stage 2 + MLP + softmax (block per graph, 64 thr) ----------------
__global__ __launch_bounds__(64) void k_mlp(const float* __restrict__ part,
                                            const int* __restrict__ gid,
                                            const float* __restrict__ fcW1,
                                            const float* __restrict__ fcb1,
                                            const float* __restrict__ fcW2,
                                            const float* __restrict__ fcb2,
                                            float* __restrict__ out) {
    __shared__ int se[2];
    __shared__ float p[64];
    __shared__ float z[10];
    __shared__ float l[10];
    __shared__ float red[2];
    const int g = blockIdx.x;
    const int t = threadIdx.x;  // 64
    if (t < 2) {
        int target = g + t;
        int lo = 0, hi = N_NODES;
        while (lo < hi) {
            int mid = (lo + hi) >> 1;
            if (gid[mid] < target) lo = mid + 1; else hi = mid;
        }
        se[t] = lo;
    }
    __syncthreads();
    const int cnt = max(se[1] - se[0], 1);
    float a = 0.f;
#pragma unroll
    for (int c = 0; c < PCHUNK; c++) a += part[((size_t)c * N_GRAPHS + g) * 64 + t];
    p[t] = a / (float)cnt;
    __syncthreads();
    if (t < 10) {
        float acc = fcb1[t];
        for (int k = 0; k < 64; k++) acc = fmaf(p[k], fcW1[k * 10 + t], acc);
        z[t] = fmaxf(acc, 0.f);
    }
    __syncthreads();
    if (t < 10) {
        float acc = fcb2[t];
        for (int k = 0; k < 10; k++) acc = fmaf(z[k], fcW2[k * 10 + t], acc);
        l[t] = acc;
    }
    __syncthreads();
    if (t == 0) {
        float m = l[0];
        for (int i = 1; i < 10; i++) m = fmaxf(m, l[i]);
        float ssum = 0.f;
        for (int i = 0; i < 10; i++) ssum += expf(l[i] - m);
        red[0] = m;
        red[1] = ssum;
    }
    __syncthreads();
    if (t < 10) out[g * 10 + t] = expf(l[t] - red[0]) / red[1];
}

// ---------------- host ----------------
extern "C" void kernel_launch(void* const* d_in, const int* in_sizes, int n_in,
                              void* d_out, int out_size, void* d_ws, size_t ws_size,
                              hipStream_t stream) {
    const float* feats = (const float*)d_in[0];
    const int* src = (const int*)d_in[1];
    const int* dst = (const int*)d_in[2];
    const int* gid = (const int*)d_in[3];
    const float* W1 = (const float*)d_in[4];
    const float* b1 = (const float*)d_in[5];
    const float* W2 = (const float*)d_in[6];
    const float* b2 = (const float*)d_in[7];
    const float* fcW1 = (const float*)d_in[8];
    const float* fcb1 = (const float*)d_in[9];
    const float* fcW2 = (const float*)d_in[10];
    const float* fcb2 = (const float*)d_in[11];
    float* out = (float*)d_out;

    char* w = (char*)d_ws;
    size_t off = 0;
    auto alloc = [&](size_t bytes) -> void* {
        void* p = w + off;
        off = (off + bytes + 255) & ~(size_t)255;
        return p;
    };
    int* cnt_out = (int*)alloc(N_NODES * 4);
    int* rp      = (int*)alloc((N_NODES + 1) * 4);
    int* cols    = (int*)alloc((size_t)N_EDGES * 4);                         // 6.4 MB tight CSR
    int* Pd      = (int*)alloc(NBUCK * SBLK * 4);                            // 400 KB
    int* Ps      = (int*)alloc(NBUCK * SBLK * 4);
    int* Td      = (int*)alloc(NBUCK * 4);
    int* Ts      = (int*)alloc(NBUCK * 4);
    int* Bd      = (int*)alloc((NBUCK + 1) * 4);
    int* Bs      = (int*)alloc((NBUCK + 1) * 4);
    unsigned int* pb  = (unsigned int*)alloc((size_t)N_EDGES * 4);           // 6.4 MB packed
    unsigned char* sb = (unsigned char*)alloc((size_t)N_EDGES);              // 1.6 MB
    unsigned short* Wt1 = (unsigned short*)alloc(128 * 128 * 2);
    unsigned short* Wt2 = (unsigned short*)alloc(64 * 128 * 2);
    unsigned char* g1 = (unsigned char*)alloc((size_t)N_NODES * 128);        // fp8 e4m3, 12.8 MB
    unsigned short* h1 = (unsigned short*)alloc((size_t)N_NODES * 128 * 2);  // bf16 row-major
    unsigned char* g2 = (unsigned char*)alloc((size_t)N_NODES * 64);         // fp8 e4m3, 6.4 MB
    unsigned short* h2 = (unsigned short*)alloc((size_t)N_NODES * 64 * 2);   // bf16 row-major
    float* part = (float*)alloc((size_t)PCHUNK * N_GRAPHS * 64 * 4);         // 256 KB pooling partials

    // build pipeline (bucket sort; no scattered device atomics, no memsets)
    k_hist2<<<SBLK + NB_PREP, 1024, 0, stream>>>(src, dst, Pd, Ps, W1, W2, Wt1, Wt2);
    k_scanA<<<2 * NBUCK, 128, 0, stream>>>(Pd, Ps, Td, Ts);
    k_scanB<<<1, 1024, 0, stream>>>(Td, Ts, Bd, Bs);
    k_scatter<<<2 * SBLK, 1024, 0, stream>>>(src, dst, Pd, Ps, Bd, Bs, pb, sb);
    k_finalize<<<NBUCK, 256, 0, stream>>>(pb, Bd, sb, Bs, rp, cnt_out, cols);

    // layer 1 (g1 fp8)
    k_gemm_mfma<128, false, true><<<dim3(N_NODES / 32, 2), 256, 0, stream>>>(feats, Wt1, cnt_out, g1);
    k_spmm128f8<<<N_NODES / 4, 256, 0, stream>>>((const unsigned int*)g1, rp, cols, b1, (uint2*)h1);

    // layer 2 (g2 fp8)
    k_gemm_mfma<64, true, true><<<dim3(N_NODES / 32, 1), 256, 0, stream>>>(h1, Wt2, cnt_out, g2);
    k_spmm64f8<<<N_NODES / 4, 256, 0, stream>>>((const unsigned int*)g2, rp, cols, b2, (uint2*)h2);

    // pooling (parallel, 2-stage) + MLP + softmax
    k_pool<<<dim3(PCHUNK, N_GRAPHS), 256, 0, stream>>>(h2, gid, part);
    k_mlp<<<N_GRAPHS, 64, 0, stream>>>(part, gid, fcW1, fcb1, fcW2, fcb2, out);
}